// Round 3
// baseline (1743.349 us; speedup 1.0000x reference)
//
#include <hip/hip_runtime.h>
#include <hip/hip_bf16.h>

#define LL 80
#define NPIX 784
#define PBATCH 15680

#define BM 64
#define BN 64
#define BK 16

#define DI __device__ __forceinline__

DI float b2f(__hip_bfloat16 x) { return __bfloat162float(x); }

// F=1: buffer holds f32; F=0: buffer holds bf16
template <int F> DI float LD(const void* p, int i) {
    if (F) return ((const float*)p)[i];
    return b2f(((const __hip_bfloat16*)p)[i]);
}

DI float fast_tanh(float x) {
    float e = __expf(2.0f * x);          // saturates cleanly at +-inf
    return 1.0f - 2.0f / (e + 1.0f);
}
DI float fast_sigmoid(float x) { return 1.0f / (1.0f + __expf(-x)); }

// ---------------- dtype probe: bf16 view of ~N(0,0.02) weights is sane; ----------------
// bf16 view of f32 bits contains wild magnitudes / NaN in ~half the half-words.
__global__ __launch_bounds__(256) void detect_dtype(const void* probe, int n, int* flag) {
    __shared__ int bad;
    if (threadIdx.x == 0) bad = 0;
    __syncthreads();
    int c = 0;
    for (int i = threadIdx.x; i < n; i += 256) {
        float v = b2f(((const __hip_bfloat16*)probe)[i]);
        if (!(fabsf(v) < 1000.0f)) c++;   // true for huge OR NaN
    }
    if (c) atomicAdd(&bad, c);
    __syncthreads();
    if (threadIdx.x == 0) *flag = (bad > 8) ? 1 : 0;   // 1 => inputs are f32
}

// ---------------- u = fca_w @ fc3_w ; c0 = fc3_b . fca_w + fca_b ----------------
template <int F>
DI void prep_u_core(const void* fc3_w, const void* fc3_b,
                    const void* fca_w, const void* fca_b,
                    float* u, float* c0, float* red) {
    if (blockIdx.x < 4) {
        int k = blockIdx.x * 256 + threadIdx.x;
        float acc = 0.f;
        for (int j = 0; j < 1024; j++)
            acc += LD<F>(fca_w, j) * LD<F>(fc3_w, j * 1024 + k);
        u[k] = acc;
    } else {
        float acc = 0.f;
        for (int j = threadIdx.x; j < 1024; j += 256)
            acc += LD<F>(fc3_b, j) * LD<F>(fca_w, j);
        red[threadIdx.x] = acc;
        __syncthreads();
        for (int s = 128; s > 0; s >>= 1) {
            if (threadIdx.x < s) red[threadIdx.x] += red[threadIdx.x + s];
            __syncthreads();
        }
        if (threadIdx.x == 0) *c0 = red[0] + LD<F>(fca_b, 0);
    }
}

__global__ __launch_bounds__(256) void prep_u(
    const int* flag, const void* fc3_w, const void* fc3_b,
    const void* fca_w, const void* fca_b, float* u, float* c0) {
    __shared__ float red[256];
    if (*flag) prep_u_core<1>(fc3_w, fc3_b, fca_w, fca_b, u, c0, red);
    else       prep_u_core<0>(fc3_w, fc3_b, fca_w, fca_b, u, c0, red);
}

// ---------------- tiled GEMM core: C[m,n] = sum_k A[m,k]*(W[n,k](+W[n,k+wdual])) + bias[n]
template <int AF, int WF>
DI void gemm_core(float (*As)[BM + 4], float (*Ws)[BN + 4],
                  const void* Aptr, int lda, const void* W, int ldw, int wdual,
                  const void* bias, float* Cf, int ldc,
                  int M, int N, int K, int bx, int by) {
    const int tid = threadIdx.x;
    const int tx = tid & 15, ty = tid >> 4;
    const int m0 = by * BM, n0 = bx * BN;
    float acc[4][4] = {};

    for (int k0 = 0; k0 < K; k0 += BK) {
#pragma unroll
        for (int i = 0; i < 4; i++) {
            int idx = tid + i * 256;
            int kk = idx & 15, mm = idx >> 4;
            int m = m0 + mm, k = k0 + kk;
            As[kk][mm] = (m < M && k < K) ? LD<AF>(Aptr, m * lda + k) : 0.f;
        }
#pragma unroll
        for (int i = 0; i < 4; i++) {
            int idx = tid + i * 256;
            int kk = idx & 15, nn = idx >> 4;
            int n = n0 + nn, k = k0 + kk;
            float w = 0.f;
            if (n < N && k < K) {
                w = LD<WF>(W, n * ldw + k);
                if (wdual) w += LD<WF>(W, n * ldw + k + wdual);
            }
            Ws[kk][nn] = w;
        }
        __syncthreads();
#pragma unroll
        for (int kk = 0; kk < BK; kk++) {
            float4 av = *(const float4*)(&As[kk][ty * 4]);
            float4 wv = *(const float4*)(&Ws[kk][tx * 4]);
            float a4[4] = {av.x, av.y, av.z, av.w};
            float w4[4] = {wv.x, wv.y, wv.z, wv.w};
#pragma unroll
            for (int i = 0; i < 4; i++)
#pragma unroll
                for (int j = 0; j < 4; j++)
                    acc[i][j] += a4[i] * w4[j];
        }
        __syncthreads();
    }

    for (int i = 0; i < 4; i++) {
        int m = m0 + ty * 4 + i;
        if (m >= M) continue;
        for (int j = 0; j < 4; j++) {
            int n = n0 + tx * 4 + j;
            if (n >= N) continue;
            float v = acc[i][j];
            if (bias) v += LD<WF>(bias, n);
            Cf[m * ldc + n] = v;
        }
    }
}

// A is a raw input (dtype per flag); W/bias raw inputs
__global__ __launch_bounds__(256) void gemm_raw(
    const int* flag, const void* A, int lda,
    const void* W, int ldw, int wdual, const void* bias,
    float* Cf, int ldc, int M, int N, int K) {
    __shared__ float As[BK][BM + 4];
    __shared__ float Ws[BK][BN + 4];
    if (*flag) gemm_core<1, 1>(As, Ws, A, lda, W, ldw, wdual, bias, Cf, ldc, M, N, K, blockIdx.x, blockIdx.y);
    else       gemm_core<0, 0>(As, Ws, A, lda, W, ldw, wdual, bias, Cf, ldc, M, N, K, blockIdx.x, blockIdx.y);
}

// A is f32 workspace; W/bias raw inputs
__global__ __launch_bounds__(256) void gemm_ws(
    const int* flag, const float* A, int lda,
    const void* W, int ldw, int wdual, const void* bias,
    float* Cf, int ldc, int M, int N, int K) {
    __shared__ float As[BK][BM + 4];
    __shared__ float Ws[BK][BN + 4];
    if (*flag) gemm_core<1, 1>(As, Ws, A, lda, W, ldw, wdual, bias, Cf, ldc, M, N, K, blockIdx.x, blockIdx.y);
    else       gemm_core<1, 0>(As, Ws, A, lda, W, ldw, wdual, bias, Cf, ldc, M, N, K, blockIdx.x, blockIdx.y);
}

// 4 gate GEMMs in one launch (blockIdx.z = job), all M=320,N=1024,K=1024, A = f32 ws
__global__ __launch_bounds__(256) void gemm_gate4(
    const int* flag, const float* a, const float* nodes,
    const void* w3, const void* b3, const void* w4, const void* b4,
    const void* w5, const void* b5, const void* u3, const void* u3b,
    float* az, float* ar_, float* ah, float* u3x) {
    __shared__ float As[BK][BM + 4];
    __shared__ float Ws[BK][BN + 4];
    const float* A; const void* Wt; const void* Bs; float* C;
    int ldw, wdual;
    switch (blockIdx.z) {
        case 0:  A = a;     Wt = w3; Bs = b3;  C = az;  ldw = 2048; wdual = 1024; break;
        case 1:  A = a;     Wt = w4; Bs = b4;  C = ar_; ldw = 2048; wdual = 1024; break;
        case 2:  A = a;     Wt = w5; Bs = b5;  C = ah;  ldw = 2048; wdual = 1024; break;
        default: A = nodes; Wt = u3; Bs = u3b; C = u3x; ldw = 1024; wdual = 0;    break;
    }
    if (*flag) gemm_core<1, 1>(As, Ws, A, 1024, Wt, ldw, wdual, Bs, C, 1024, 320, 1024, 1024, blockIdx.x, blockIdx.y);
    else       gemm_core<1, 0>(As, Ws, A, 1024, Wt, ldw, wdual, Bs, C, 1024, 320, 1024, 1024, blockIdx.x, blockIdx.y);
}

// ---------------- final GEMM: out = tanh([nodes|g] @ fco_w.T + b), out dtype per flag
template <int F>
DI void final_core(float (*As)[BM + 4], float (*Ws)[BN + 4],
                   const float* nodes, const float* g,
                   const void* W, const void* bias, void* out) {
    const int tid = threadIdx.x;
    const int tx = tid & 15, ty = tid >> 4;
    const int m0 = blockIdx.y * BM, n0 = blockIdx.x * BN;
    float acc[4][4] = {};
    const int M = 320, K = 2048;

    for (int k0 = 0; k0 < K; k0 += BK) {
#pragma unroll
        for (int i = 0; i < 4; i++) {
            int idx = tid + i * 256;
            int kk = idx & 15, mm = idx >> 4;
            int m = m0 + mm, k = k0 + kk;
            float v = 0.f;
            if (m < M) {
                const float* src = (k < 1024) ? nodes : g;
                v = src[m * 1024 + (k & 1023)];
            }
            As[kk][mm] = v;
        }
#pragma unroll
        for (int i = 0; i < 4; i++) {
            int idx = tid + i * 256;
            int kk = idx & 15, nn = idx >> 4;
            int n = n0 + nn, k = k0 + kk;
            Ws[kk][nn] = LD<F>(W, n * 2048 + k);
        }
        __syncthreads();
#pragma unroll
        for (int kk = 0; kk < BK; kk++) {
            float4 av = *(const float4*)(&As[kk][ty * 4]);
            float4 wv = *(const float4*)(&Ws[kk][tx * 4]);
            float a4[4] = {av.x, av.y, av.z, av.w};
            float w4[4] = {wv.x, wv.y, wv.z, wv.w};
#pragma unroll
            for (int i = 0; i < 4; i++)
#pragma unroll
                for (int j = 0; j < 4; j++)
                    acc[i][j] += a4[i] * w4[j];
        }
        __syncthreads();
    }

    for (int i = 0; i < 4; i++) {
        int m = m0 + ty * 4 + i;
        if (m >= M) continue;
        for (int j = 0; j < 4; j++) {
            int n = n0 + tx * 4 + j;
            float v = fast_tanh(acc[i][j] + LD<F>(bias, n));
            if (F) ((float*)out)[m * 2048 + n] = v;
            else   ((__hip_bfloat16*)out)[m * 2048 + n] = __float2bfloat16(v);
        }
    }
}

__global__ __launch_bounds__(256) void gemm_final(
    const int* flag, const float* nodes, const float* g,
    const void* W, const void* bias, void* out) {
    __shared__ float As[BK][BM + 4];
    __shared__ float Ws[BK][BN + 4];
    if (*flag) final_core<1>(As, Ws, nodes, g, W, bias, out);
    else       final_core<0>(As, Ws, nodes, g, W, bias, out);
}

// ---------------- coeff[n,l] = sum_k tanh(f_wh[n,k]*f_wd[l,k])*u[k] + c0 ----------------
// torch-view layout: s[b*15680 + hw*80 + l], n = b*196 + hw   (all f32 ws)
__global__ __launch_bounds__(256) void coeff_kernel(
    const float* __restrict__ f_wh, const float* __restrict__ f_wd,
    const float* __restrict__ u, const float* __restrict__ c0p,
    float* __restrict__ s) {
    int n = blockIdx.x;  // 0..783
    __shared__ float fh[1024];
    __shared__ float uu[1024];
    for (int i = threadIdx.x; i < 1024; i += 256) {
        fh[i] = f_wh[n * 1024 + i];
        uu[i] = u[i];
    }
    __syncthreads();
    float c0 = *c0p;
    int wave = threadIdx.x >> 6, lane = threadIdx.x & 63;
    int b = n / 196, hw = n % 196;
    for (int l = wave; l < LL; l += 4) {
        const float* fd = f_wd + l * 1024;
        float p = 0.f;
        for (int k = lane; k < 1024; k += 64)
            p += fast_tanh(fh[k] * fd[k]) * uu[k];
        for (int off = 32; off > 0; off >>= 1) p += __shfl_down(p, off);
        if (lane == 0) s[b * PBATCH + hw * LL + l] = p + c0;
    }
}

// ---------------- softmax over contiguous 196-chunks (f32 ws) ----------------
__global__ __launch_bounds__(64) void softmax196(float* __restrict__ s) {
    float* p = s + blockIdx.x * 196;  // 320 chunks
    int lane = threadIdx.x;
    float v[4];
    float mx = -1e30f;
#pragma unroll
    for (int i = 0; i < 4; i++) {
        int idx = lane + i * 64;
        v[i] = (idx < 196) ? p[idx] : -1e30f;
        mx = fmaxf(mx, v[i]);
    }
    for (int off = 32; off > 0; off >>= 1) mx = fmaxf(mx, __shfl_down(mx, off));
    mx = __shfl(mx, 0);
    float sum = 0.f;
#pragma unroll
    for (int i = 0; i < 4; i++) {
        int idx = lane + i * 64;
        if (idx < 196) { v[i] = __expf(v[i] - mx); sum += v[i]; }
    }
    for (int off = 32; off > 0; off >>= 1) sum += __shfl_down(sum, off);
    sum = __shfl(sum, 0);
    float inv = 1.f / sum;
#pragma unroll
    for (int i = 0; i < 4; i++) {
        int idx = lane + i * 64;
        if (idx < 196) p[idx] = v[i] * inv;
    }
}

// ---------------- g[b,l,c] = sum_hw s[b*15680+hw*80+l] * fmap_flat[(b*196+hw)*1024+c]
template <int F>
DI void g_core(float* co, const float* s, const void* fmap, float* g, float* nodes) {
    int bl = blockIdx.x;          // b*80 + l
    int b = bl / LL, l = bl % LL;
    for (int i = threadIdx.x; i < 196; i += 256)
        co[i] = s[b * PBATCH + i * LL + l];
    __syncthreads();
    for (int c = threadIdx.x; c < 1024; c += 256) {
        int base = b * 196 * 1024 + c;
        float acc = 0.f;
        for (int hw = 0; hw < 196; hw++)
            acc += co[hw] * LD<F>(fmap, base + hw * 1024);
        g[bl * 1024 + c] = acc;
        nodes[bl * 1024 + c] = acc;
    }
}

__global__ __launch_bounds__(256) void g_kernel(
    const int* flag, const float* s, const void* fmap, float* g, float* nodes) {
    __shared__ float co[196];
    if (*flag) g_core<1>(co, s, fmap, g, nodes);
    else       g_core<0>(co, s, fmap, g, nodes);
}

// ---------------- a[b,l,:] = sum_m adj[l,m] * nodes[b,m,:] ----------------
template <int F>
DI void adj_core(float* arw, const void* adj, const float* nodes, float* a) {
    int bl = blockIdx.x;
    int b = bl / LL, l = bl % LL;
    if (threadIdx.x < LL) arw[threadIdx.x] = LD<F>(adj, l * LL + threadIdx.x);
    __syncthreads();
    for (int c = threadIdx.x; c < 1024; c += 256) {
        float acc = 0.f;
        for (int m = 0; m < LL; m++)
            acc += arw[m] * nodes[(b * LL + m) * 1024 + c];
        a[bl * 1024 + c] = acc;
    }
}

__global__ __launch_bounds__(256) void adj_kernel(
    const int* flag, const void* adj, const float* nodes, float* a) {
    __shared__ float arw[LL];
    if (*flag) adj_core<1>(arw, adj, nodes, a);
    else       adj_core<0>(arw, adj, nodes, a);
}

// ---------------- rn = sigmoid(ar + u3x) * nodes  (in-place into ar_) ----------------
__global__ void ew_r(float* ar_, const float* __restrict__ u3x,
                     const float* __restrict__ nodes, int n) {
    int i = blockIdx.x * 256 + threadIdx.x;
    if (i < n) {
        float r = fast_sigmoid(ar_[i] + u3x[i]);
        ar_[i] = r * nodes[i];
    }
}

// ---------------- nodes = (1-z)*nodes + z*tanh(ah + u5x), z = sigmoid(az+u3x) ----------------
__global__ void ew_upd(const float* __restrict__ az, const float* __restrict__ u3x,
                       const float* __restrict__ ah, const float* __restrict__ u5x,
                       float* __restrict__ nodes, int n) {
    int i = blockIdx.x * 256 + threadIdx.x;
    if (i < n) {
        float z = fast_sigmoid(az[i] + u3x[i]);
        float h = fast_tanh(ah[i] + u5x[i]);
        float nd = nodes[i];
        nodes[i] = (1.f - z) * nd + z * h;
    }
}

extern "C" void kernel_launch(void* const* d_in, const int* in_sizes, int n_in,
                              void* d_out, int out_size, void* d_ws, size_t ws_size,
                              hipStream_t stream) {
    const void* fmap  = d_in[0];
    const void* word  = d_in[1];
    const void* adjm  = d_in[2];
    const void* fc1_w = d_in[3];
    const void* fc2_w = d_in[4];
    const void* fc3_w = d_in[5];
    const void* fc3_b = d_in[6];
    const void* fca_w = d_in[7];
    const void* fca_b = d_in[8];
    const void* w3    = d_in[9];
    const void* b3    = d_in[10];
    const void* u3    = d_in[11];
    const void* u3b   = d_in[12];
    const void* w4    = d_in[13];
    const void* b4    = d_in[14];
    const void* w5    = d_in[15];
    const void* b5    = d_in[16];
    const void* u5    = d_in[17];
    const void* u5b   = d_in[18];
    const void* fco_w = d_in[19];
    const void* fco_b = d_in[20];

    // ---- workspace: flag + 9.18 MB of f32 buffers ----
    int*   flag  = (int*)d_ws;
    float* ws    = (float*)d_ws + 16;
    float* g     = ws;                  // 327680 (persistent)
    float* nodes = g + 327680;          // 327680 (persistent)
    float* R     = nodes + 327680;      // overlay region
    // semantic overlay (948,496 floats)
    float* f_wh = R;                    // 802816
    float* f_wd = f_wh + 802816;        // 81920
    float* u    = f_wd + 81920;         // 1024
    float* c0   = u + 1024;             // 16
    float* s    = c0 + 16;              // 62720
    // GGNN overlay (1,638,400 floats) — reuses R
    float* a    = R;                    // u5x aliases this after gate4
    float* az   = a + 327680;
    float* ar_  = az + 327680;          // rn aliases this after ew_r
    float* ah   = ar_ + 327680;
    float* u3x  = ah + 327680;
    float* u5x  = a;

    // ---- dtype detection (probe fc1_w, ~N(0,0.02)) ----
    detect_dtype<<<1, 256, 0, stream>>>(fc1_w, 4096, flag);

    // ---- semantic stage ----
    prep_u<<<5, 256, 0, stream>>>(flag, fc3_w, fc3_b, fca_w, fca_b, u, c0);
    gemm_raw<<<dim3(16, 13), 256, 0, stream>>>(flag, fmap, 1024, fc1_w, 1024, 0, nullptr,
                                               f_wh, 1024, NPIX, 1024, 1024);
    gemm_raw<<<dim3(16, 2), 256, 0, stream>>>(flag, word, 300, fc2_w, 300, 0, nullptr,
                                              f_wd, 1024, LL, 1024, 300);
    coeff_kernel<<<NPIX, 256, 0, stream>>>(f_wh, f_wd, u, c0, s);
    softmax196<<<320, 64, 0, stream>>>(s);
    g_kernel<<<320, 256, 0, stream>>>(flag, s, fmap, g, nodes);

    // ---- GGNN: 3 time steps ----
    for (int t = 0; t < 3; t++) {
        adj_kernel<<<320, 256, 0, stream>>>(flag, adjm, nodes, a);
        gemm_gate4<<<dim3(16, 5, 4), 256, 0, stream>>>(flag, a, nodes, w3, b3, w4, b4,
                                                       w5, b5, u3, u3b, az, ar_, ah, u3x);
        ew_r<<<1280, 256, 0, stream>>>(ar_, u3x, nodes, 327680);
        gemm_ws<<<dim3(16, 5), 256, 0, stream>>>(flag, ar_, 1024, u5, 1024, 0, u5b,
                                                 u5x, 1024, 320, 1024, 1024);
        ew_upd<<<1280, 256, 0, stream>>>(az, u3x, ah, u5x, nodes, 327680);
    }

    // ---- output: tanh([nodes|g] @ fco_w.T + b) ----
    gemm_final<<<dim3(32, 5), 256, 0, stream>>>(flag, nodes, g, fco_w, fco_b, d_out);
}

// Round 4
// 1057.366 us; speedup vs baseline: 1.6488x; 1.6488x over previous
//
#include <hip/hip_runtime.h>
#include <hip/hip_bf16.h>

#define LL 80
#define NPIX 784
#define PBATCH 15680

#define BM 64
#define BN 64
#define BK 16

#define DI __device__ __forceinline__

DI float b2f(__hip_bfloat16 x) { return __bfloat162float(x); }

// F=1: buffer holds f32; F=0: buffer holds bf16
template <int F> DI float LD(const void* p, int i) {
    if (F) return ((const float*)p)[i];
    return b2f(((const __hip_bfloat16*)p)[i]);
}

DI float fast_tanh(float x) {
    float e = __expf(2.0f * x);          // saturates cleanly at +-inf
    return 1.0f - 2.0f / (e + 1.0f);
}
DI float fast_sigmoid(float x) { return 1.0f / (1.0f + __expf(-x)); }

// ---------------- dtype probe (proven in R3): bf16 view of f32 bits is wild ----------------
__global__ __launch_bounds__(256) void detect_dtype(const void* probe, int n, int* flag) {
    __shared__ int bad;
    if (threadIdx.x == 0) bad = 0;
    __syncthreads();
    int c = 0;
    for (int i = threadIdx.x; i < n; i += 256) {
        float v = b2f(((const __hip_bfloat16*)probe)[i]);
        if (!(fabsf(v) < 1000.0f)) c++;
    }
    if (c) atomicAdd(&bad, c);
    __syncthreads();
    if (threadIdx.x == 0) *flag = (bad > 8) ? 1 : 0;   // 1 => inputs are f32
}

// ---------------- u = fca_w @ fc3_w ; c0 = fc3_b . fca_w + fca_b ----------------
template <int F>
DI void prep_u_core(const void* fc3_w, const void* fc3_b,
                    const void* fca_w, const void* fca_b,
                    float* u, float* c0, float* red) {
    if (blockIdx.x < 4) {
        int k = blockIdx.x * 256 + threadIdx.x;
        float acc = 0.f;
        for (int j = 0; j < 1024; j++)
            acc += LD<F>(fca_w, j) * LD<F>(fc3_w, j * 1024 + k);
        u[k] = acc;
    } else {
        float acc = 0.f;
        for (int j = threadIdx.x; j < 1024; j += 256)
            acc += LD<F>(fc3_b, j) * LD<F>(fca_w, j);
        red[threadIdx.x] = acc;
        __syncthreads();
        for (int s = 128; s > 0; s >>= 1) {
            if (threadIdx.x < s) red[threadIdx.x] += red[threadIdx.x + s];
            __syncthreads();
        }
        if (threadIdx.x == 0) *c0 = red[0] + LD<F>(fca_b, 0);
    }
}

__global__ __launch_bounds__(256) void prep_u(
    const int* flag, const void* fc3_w, const void* fc3_b,
    const void* fca_w, const void* fca_b, float* u, float* c0) {
    __shared__ float red[256];
    if (*flag) prep_u_core<1>(fc3_w, fc3_b, fca_w, fca_b, u, c0, red);
    else       prep_u_core<0>(fc3_w, fc3_b, fca_w, fca_b, u, c0, red);
}

// ---------------- operand loaders ----------------
struct AldF32 {
    const float* p; int ld;
    DI float ld_(int m, int k, bool ok) const { return ok ? p[m * ld + k] : 0.f; }
};
template <int F> struct AldRaw {
    const void* p; int ld;
    DI float ld_(int m, int k, bool ok) const { return ok ? LD<F>(p, m * ld + k) : 0.f; }
};
struct AldCat {   // row m = [nodes[m,:1024] | g[m,:1024]]
    const float* nd; const float* gg;
    DI float ld_(int m, int k, bool ok) const {
        if (!ok) return 0.f;
        const float* s = (k < 1024) ? nd : gg;
        return s[m * 1024 + (k & 1023)];
    }
};
template <int F> struct AldU5 {  // rn = sigmoid(ar + u3x + b4 + u3b) * nodes  (fused ew_r)
    const float* ar; const float* u3x; const float* nodes;
    const void* b4; const void* u3b;
    DI float ld_(int m, int k, bool ok) const {
        if (!ok) return 0.f;
        int i = m * 1024 + k;
        float r = fast_sigmoid(ar[i] + u3x[i] + LD<F>(b4, k) + LD<F>(u3b, k));
        return r * nodes[i];
    }
};
template <int F> struct Wld {    // W[n,k] (+ W[n,k+dual] for the [a,a] concat fold)
    const void* p; int ld; int dual;
    DI float ld_(int n, int k, bool ok) const {
        if (!ok) return 0.f;
        float w = LD<F>(p, n * ld + k);
        if (dual) w += LD<F>(p, n * ld + k + dual);
        return w;
    }
};

// ---------------- tiled GEMM core (64x64 tile, 256 thr, split-K via [kb,ke)) ----------------
template <class AL, class WL>
DI void gcore(const AL& A, const WL& W, float* C, int ldc,
              int M, int N, int kb, int ke, int bx, int by, int atom) {
    __shared__ float As[BK][BM + 4];
    __shared__ float Ws[BK][BN + 4];
    const int tid = threadIdx.x;
    const int tx = tid & 15, ty = tid >> 4;
    const int m0 = by * BM, n0 = bx * BN;
    float acc[4][4] = {};

    for (int k0 = kb; k0 < ke; k0 += BK) {
#pragma unroll
        for (int i = 0; i < 4; i++) {
            int idx = tid + i * 256;
            int kk = idx & 15, mm = idx >> 4;
            int m = m0 + mm, k = k0 + kk;
            As[kk][mm] = A.ld_(m, k, m < M && k < ke);
        }
#pragma unroll
        for (int i = 0; i < 4; i++) {
            int idx = tid + i * 256;
            int kk = idx & 15, nn = idx >> 4;
            int n = n0 + nn, k = k0 + kk;
            Ws[kk][nn] = W.ld_(n, k, n < N && k < ke);
        }
        __syncthreads();
#pragma unroll
        for (int kk = 0; kk < BK; kk++) {
            float4 av = *(const float4*)(&As[kk][ty * 4]);
            float4 wv = *(const float4*)(&Ws[kk][tx * 4]);
            float a4[4] = {av.x, av.y, av.z, av.w};
            float w4[4] = {wv.x, wv.y, wv.z, wv.w};
#pragma unroll
            for (int i = 0; i < 4; i++)
#pragma unroll
                for (int j = 0; j < 4; j++)
                    acc[i][j] += a4[i] * w4[j];
        }
        __syncthreads();
    }

    for (int i = 0; i < 4; i++) {
        int m = m0 + ty * 4 + i;
        if (m >= M) continue;
        for (int j = 0; j < 4; j++) {
            int n = n0 + tx * 4 + j;
            if (n >= N) continue;
            if (atom) atomicAdd(&C[m * ldc + n], acc[i][j]);
            else      C[m * ldc + n] = acc[i][j];
        }
    }
}

// A = raw input (dtype per flag), W raw. grid.z = k-split index.
__global__ __launch_bounds__(256) void gemm_in(
    const int* flag, const void* Ap, int lda,
    const void* Wp, int ldw, int wdual,
    float* C, int ldc, int M, int N, int K, int ksl, int atom) {
    int kb = blockIdx.z * ksl;
    int ke = kb + ksl; if (ke > K) ke = K;
    if (*flag) { AldRaw<1> A{Ap, lda}; Wld<1> W{Wp, ldw, wdual};
        gcore(A, W, C, ldc, M, N, kb, ke, blockIdx.x, blockIdx.y, atom); }
    else       { AldRaw<0> A{Ap, lda}; Wld<0> W{Wp, ldw, wdual};
        gcore(A, W, C, ldc, M, N, kb, ke, blockIdx.x, blockIdx.y, atom); }
}

// 4 gate GEMMs x 2 k-splits: grid.z = job*2 + split. All M=320,N=1024,K=1024, atomic.
__global__ __launch_bounds__(256) void gemm_gate(
    const int* flag, const float* a, const float* nodes,
    const void* w3, const void* w4p, const void* w5p, const void* u3,
    float* az, float* ar_, float* ah, float* u3x) {
    int job = blockIdx.z >> 1, s = blockIdx.z & 1;
    const float* Ap; const void* Wp; float* C; int ldw, dual;
    switch (job) {
        case 0:  Ap = a;     Wp = w3;  C = az;  ldw = 2048; dual = 1024; break;
        case 1:  Ap = a;     Wp = w4p; C = ar_; ldw = 2048; dual = 1024; break;
        case 2:  Ap = a;     Wp = w5p; C = ah;  ldw = 2048; dual = 1024; break;
        default: Ap = nodes; Wp = u3;  C = u3x; ldw = 1024; dual = 0;    break;
    }
    int kb = s * 512, ke = kb + 512;
    AldF32 A{Ap, 1024};
    if (*flag) { Wld<1> W{Wp, ldw, dual};
        gcore(A, W, C, 1024, 320, 1024, kb, ke, blockIdx.x, blockIdx.y, 1); }
    else       { Wld<0> W{Wp, ldw, dual};
        gcore(A, W, C, 1024, 320, 1024, kb, ke, blockIdx.x, blockIdx.y, 1); }
}

// u5 GEMM with fused r-gate A-operand; 4 k-splits, atomic.
__global__ __launch_bounds__(256) void gemm_u5(
    const int* flag, const float* ar_, const float* u3x, const float* nodes,
    const void* b4, const void* u3b, const void* u5w, float* u5x) {
    int kb = blockIdx.z * 256, ke = kb + 256;
    if (*flag) { AldU5<1> A{ar_, u3x, nodes, b4, u3b}; Wld<1> W{u5w, 1024, 0};
        gcore(A, W, u5x, 1024, 320, 1024, kb, ke, blockIdx.x, blockIdx.y, 1); }
    else       { AldU5<0> A{ar_, u3x, nodes, b4, u3b}; Wld<0> W{u5w, 1024, 0};
        gcore(A, W, u5x, 1024, 320, 1024, kb, ke, blockIdx.x, blockIdx.y, 1); }
}

// final GEMM partials: fC = [nodes|g] @ fco_w.T  (no bias/act yet); 4 k-splits, atomic.
__global__ __launch_bounds__(256) void gemm_fin(
    const int* flag, const float* nodes, const float* g,
    const void* fco_w, float* fC) {
    int kb = blockIdx.z * 512, ke = kb + 512;
    AldCat A{nodes, g};
    if (*flag) { Wld<1> W{fco_w, 2048, 0};
        gcore(A, W, fC, 2048, 320, 2048, kb, ke, blockIdx.x, blockIdx.y, 1); }
    else       { Wld<0> W{fco_w, 2048, 0};
        gcore(A, W, fC, 2048, 320, 2048, kb, ke, blockIdx.x, blockIdx.y, 1); }
}

__global__ void fin_combine(const int* flag, const float* fC, const void* fco_b,
                            void* out, int n) {
    int i = blockIdx.x * 256 + threadIdx.x;
    if (i >= n) return;
    int c = i & 2047;
    if (*flag) {
        float v = fast_tanh(fC[i] + LD<1>(fco_b, c));
        ((float*)out)[i] = v;
    } else {
        float v = fast_tanh(fC[i] + LD<0>(fco_b, c));
        ((__hip_bfloat16*)out)[i] = __float2bfloat16(v);
    }
}

// ---------------- coeff[n,l] = sum_k tanh(f_wh[n,k]*f_wd[l,k])*u[k] + c0 ----------------
// torch-view layout: s[b*15680 + hw*80 + l]; grid = (784, 2) — 40 l's per block
__global__ __launch_bounds__(256) void coeff_kernel(
    const float* __restrict__ f_wh, const float* __restrict__ f_wd,
    const float* __restrict__ u, const float* __restrict__ c0p,
    float* __restrict__ s) {
    int n = blockIdx.x;  // 0..783
    __shared__ float fh[1024];
    __shared__ float uu[1024];
    for (int i = threadIdx.x; i < 1024; i += 256) {
        fh[i] = f_wh[n * 1024 + i];
        uu[i] = u[i];
    }
    __syncthreads();
    float c0 = *c0p;
    int wave = threadIdx.x >> 6, lane = threadIdx.x & 63;
    int b = n / 196, hw = n % 196;
    int l0 = blockIdx.y * 40;
    for (int l = l0 + wave; l < l0 + 40; l += 4) {
        const float* fd = f_wd + l * 1024;
        float p = 0.f;
        for (int k = lane; k < 1024; k += 64)
            p += fast_tanh(fh[k] * fd[k]) * uu[k];
        for (int off = 32; off > 0; off >>= 1) p += __shfl_down(p, off);
        if (lane == 0) s[b * PBATCH + hw * LL + l] = p + c0;
    }
}

// ---------------- softmax over contiguous 196-chunks ----------------
__global__ __launch_bounds__(64) void softmax196(float* __restrict__ s) {
    float* p = s + blockIdx.x * 196;
    int lane = threadIdx.x;
    float v[4];
    float mx = -1e30f;
#pragma unroll
    for (int i = 0; i < 4; i++) {
        int idx = lane + i * 64;
        v[i] = (idx < 196) ? p[idx] : -1e30f;
        mx = fmaxf(mx, v[i]);
    }
    for (int off = 32; off > 0; off >>= 1) mx = fmaxf(mx, __shfl_down(mx, off));
    mx = __shfl(mx, 0);
    float sum = 0.f;
#pragma unroll
    for (int i = 0; i < 4; i++) {
        int idx = lane + i * 64;
        if (idx < 196) { v[i] = __expf(v[i] - mx); sum += v[i]; }
    }
    for (int off = 32; off > 0; off >>= 1) sum += __shfl_down(sum, off);
    sum = __shfl(sum, 0);
    float inv = 1.f / sum;
#pragma unroll
    for (int i = 0; i < 4; i++) {
        int idx = lane + i * 64;
        if (idx < 196) p[idx] = v[i] * inv;
    }
}

// ---------------- g[b,l,c] = sum_hw s[..] * fmap ; grid (320, 4), one c per thread ----------------
template <int F>
DI void g_core(float* co, const float* s, const void* fmap, float* g, float* nodes) {
    int bl = blockIdx.x;
    int b = bl / LL, l = bl % LL;
    for (int i = threadIdx.x; i < 196; i += 256)
        co[i] = s[b * PBATCH + i * LL + l];
    __syncthreads();
    int c = blockIdx.y * 256 + threadIdx.x;
    int base = b * 196 * 1024 + c;
    float acc = 0.f;
    for (int hw = 0; hw < 196; hw++)
        acc += co[hw] * LD<F>(fmap, base + hw * 1024);
    g[bl * 1024 + c] = acc;
    nodes[bl * 1024 + c] = acc;
}

__global__ __launch_bounds__(256) void g_kernel(
    const int* flag, const float* s, const void* fmap, float* g, float* nodes) {
    __shared__ float co[196];
    if (*flag) g_core<1>(co, s, fmap, g, nodes);
    else       g_core<0>(co, s, fmap, g, nodes);
}

// ---------------- a[b,l,c] = sum_m adj[l,m]*nodes[b,m,c] ; grid (320, 4) ----------------
template <int F>
DI void adj_core(float* arw, const void* adj, const float* nodes, float* a) {
    int bl = blockIdx.x;
    int b = bl / LL, l = bl % LL;
    if (threadIdx.x < LL) arw[threadIdx.x] = LD<F>(adj, l * LL + threadIdx.x);
    __syncthreads();
    int c = blockIdx.y * 256 + threadIdx.x;
    float acc = 0.f;
    for (int m = 0; m < LL; m++)
        acc += arw[m] * nodes[(b * LL + m) * 1024 + c];
    a[bl * 1024 + c] = acc;
}

__global__ __launch_bounds__(256) void adj_kernel(
    const int* flag, const void* adj, const float* nodes, float* a) {
    __shared__ float arw[LL];
    if (*flag) adj_core<1>(arw, adj, nodes, a);
    else       adj_core<0>(arw, adj, nodes, a);
}

// ---------------- nodes = (1-z)*nodes + z*tanh(ah+b5+u5x+u5b), z=sigmoid(az+b3+u3x+u3b) ----------------
template <int F>
DI void ewu(const float* az, const float* u3x, const float* ah, const float* u5x,
            const void* b3, const void* u3b, const void* b5, const void* u5b,
            float* nodes, int i) {
    int c = i & 1023;
    float z = fast_sigmoid(az[i] + u3x[i] + LD<F>(b3, c) + LD<F>(u3b, c));
    float h = fast_tanh(ah[i] + u5x[i] + LD<F>(b5, c) + LD<F>(u5b, c));
    nodes[i] = (1.f - z) * nodes[i] + z * h;
}

__global__ void ew_upd(const int* flag,
                       const float* az, const float* u3x, const float* ah, const float* u5x,
                       const void* b3, const void* u3b, const void* b5, const void* u5b,
                       float* nodes, int n) {
    int i = blockIdx.x * 256 + threadIdx.x;
    if (i >= n) return;
    if (*flag) ewu<1>(az, u3x, ah, u5x, b3, u3b, b5, u5b, nodes, i);
    else       ewu<0>(az, u3x, ah, u5x, b3, u3b, b5, u5b, nodes, i);
}

extern "C" void kernel_launch(void* const* d_in, const int* in_sizes, int n_in,
                              void* d_out, int out_size, void* d_ws, size_t ws_size,
                              hipStream_t stream) {
    const void* fmap  = d_in[0];
    const void* word  = d_in[1];
    const void* adjm  = d_in[2];
    const void* fc1_w = d_in[3];
    const void* fc2_w = d_in[4];
    const void* fc3_w = d_in[5];
    const void* fc3_b = d_in[6];
    const void* fca_w = d_in[7];
    const void* fca_b = d_in[8];
    const void* w3    = d_in[9];
    const void* b3    = d_in[10];
    const void* u3    = d_in[11];
    const void* u3b   = d_in[12];
    const void* w4    = d_in[13];
    const void* b4    = d_in[14];
    const void* w5    = d_in[15];
    const void* b5    = d_in[16];
    const void* u5    = d_in[17];
    const void* u5b   = d_in[18];
    const void* fco_w = d_in[19];
    const void* fco_b = d_in[20];

    // ---- workspace: same 9.18 MB footprint proven in R3 ----
    int*   flag  = (int*)d_ws;
    float* ws    = (float*)d_ws + 16;
    float* g     = ws;                  // 327680 (persistent)
    float* nodes = g + 327680;          // 327680 (persistent)
    float* R     = nodes + 327680;      // overlay region (1,638,400 floats)
    // semantic overlay
    float* f_wh = R;                    // 802816
    float* f_wd = f_wh + 802816;        // 81920
    float* u    = f_wd + 81920;         // 1024
    float* c0   = u + 1024;             // 16
    float* s    = c0 + 16;              // 62720
    // GGNN overlay (reuses R): a, az, ar, ah, u3x ; u5x aliases a after gate4
    float* a    = R;
    float* az   = a + 327680;
    float* ar_  = az + 327680;
    float* ah   = ar_ + 327680;
    float* u3x  = ah + 327680;
    float* u5x  = a;                    // a dead after gemm_gate
    // final overlay (reuses R): fC 655360
    float* fC   = R;

    // ---- dtype detection ----
    detect_dtype<<<1, 256, 0, stream>>>(fc1_w, 4096, flag);

    // ---- semantic stage ----
    prep_u<<<5, 256, 0, stream>>>(flag, fc3_w, fc3_b, fca_w, fca_b, u, c0);
    hipMemsetAsync(f_wh, 0, 802816 * sizeof(float), stream);
    // f_wh = fmap_view(784,1024) @ fc1_w.T   — split-K 2, atomic
    gemm_in<<<dim3(16, 13, 2), 256, 0, stream>>>(flag, fmap, 1024, fc1_w, 1024, 0,
                                                 f_wh, 1024, NPIX, 1024, 1024, 512, 1);
    // f_wd = word(80,300) @ fc2_w.T — single split, plain store
    gemm_in<<<dim3(16, 2, 1), 256, 0, stream>>>(flag, word, 300, fc2_w, 300, 0,
                                                f_wd, 1024, LL, 1024, 300, 304, 0);
    coeff_kernel<<<dim3(NPIX, 2), 256, 0, stream>>>(f_wh, f_wd, u, c0, s);
    softmax196<<<320, 64, 0, stream>>>(s);
    g_kernel<<<dim3(320, 4), 256, 0, stream>>>(flag, s, fmap, g, nodes);

    // ---- GGNN: 3 time steps ----
    for (int t = 0; t < 3; t++) {
        adj_kernel<<<dim3(320, 4), 256, 0, stream>>>(flag, adjm, nodes, a);
        hipMemsetAsync(az, 0, 4u * 327680 * sizeof(float), stream);  // az,ar,ah,u3x
        gemm_gate<<<dim3(16, 5, 8), 256, 0, stream>>>(flag, a, nodes, w3, w4, w5, u3,
                                                      az, ar_, ah, u3x);
        hipMemsetAsync(u5x, 0, 327680 * sizeof(float), stream);      // u5x aliases a
        gemm_u5<<<dim3(16, 5, 4), 256, 0, stream>>>(flag, ar_, u3x, nodes, b4, u3b,
                                                    u5, u5x);
        ew_upd<<<1280, 256, 0, stream>>>(flag, az, u3x, ah, u5x,
                                         b3, u3b, b5, u5b, nodes, 327680);
    }

    // ---- output: tanh([nodes|g] @ fco_w.T + fco_b) ----
    hipMemsetAsync(fC, 0, 655360 * sizeof(float), stream);
    gemm_fin<<<dim3(32, 5, 4), 256, 0, stream>>>(flag, nodes, g, fco_w, fC);
    fin_combine<<<2560, 256, 0, stream>>>(flag, fC, fco_b, d_out, 655360);
}

// Round 5
// 727.474 us; speedup vs baseline: 2.3964x; 1.4535x over previous
//
#include <hip/hip_runtime.h>
#include <hip/hip_bf16.h>

#define LL 80
#define NPIX 784
#define PBATCH 15680

#define BM 64
#define BN 64
#define BK 16

#define DI __device__ __forceinline__

typedef short bf8v __attribute__((ext_vector_type(8)));    // 8 bf16 (4 VGPRs)
typedef short short4v __attribute__((ext_vector_type(4))); // 8B LDS store
typedef float f32x4 __attribute__((ext_vector_type(4)));   // MFMA acc

DI float b2f(__hip_bfloat16 x) { return __bfloat162float(x); }

// f32 -> bf16 bits, round-nearest-even (manual; inputs finite)
DI short f2b(float x) {
    unsigned int b = __float_as_uint(x);
    b += 0x7fffu + ((b >> 16) & 1u);
    return (short)(b >> 16);
}

// F=1: buffer holds f32; F=0: buffer holds bf16
template <int F> DI float LD(const void* p, int i) {
    if (F) return ((const float*)p)[i];
    return b2f(((const __hip_bfloat16*)p)[i]);
}

DI float fast_tanh(float x) {
    float e = __expf(2.0f * x);
    return 1.0f - 2.0f / (e + 1.0f);
}
DI float fast_sigmoid(float x) { return 1.0f / (1.0f + __expf(-x)); }

// ---------------- dtype probe (proven R3/R4) ----------------
__global__ __launch_bounds__(256) void detect_dtype(const void* probe, int n, int* flag) {
    __shared__ int bad;
    if (threadIdx.x == 0) bad = 0;
    __syncthreads();
    int c = 0;
    for (int i = threadIdx.x; i < n; i += 256) {
        float v = b2f(((const __hip_bfloat16*)probe)[i]);
        if (!(fabsf(v) < 1000.0f)) c++;
    }
    if (c) atomicAdd(&bad, c);
    __syncthreads();
    if (threadIdx.x == 0) *flag = (bad > 8) ? 1 : 0;   // 1 => inputs are f32
}

// ---------------- u = fca_w @ fc3_w ; c0 = fc3_b . fca_w + fca_b ----------------
template <int F>
DI void prep_u_core(const void* fc3_w, const void* fc3_b,
                    const void* fca_w, const void* fca_b,
                    float* u, float* c0, float* red) {
    if (blockIdx.x < 4) {
        int k = blockIdx.x * 256 + threadIdx.x;
        float acc = 0.f;
        for (int j = 0; j < 1024; j++)
            acc += LD<F>(fca_w, j) * LD<F>(fc3_w, j * 1024 + k);
        u[k] = acc;
    } else {
        float acc = 0.f;
        for (int j = threadIdx.x; j < 1024; j += 256)
            acc += LD<F>(fc3_b, j) * LD<F>(fca_w, j);
        red[threadIdx.x] = acc;
        __syncthreads();
        for (int s = 128; s > 0; s >>= 1) {
            if (threadIdx.x < s) red[threadIdx.x] += red[threadIdx.x + s];
            __syncthreads();
        }
        if (threadIdx.x == 0) *c0 = red[0] + LD<F>(fca_b, 0);
    }
}

__global__ __launch_bounds__(256) void prep_u(
    const int* flag, const void* fc3_w, const void* fc3_b,
    const void* fca_w, const void* fca_b, float* u, float* c0) {
    __shared__ float red[256];
    if (*flag) prep_u_core<1>(fc3_w, fc3_b, fca_w, fca_b, u, c0, red);
    else       prep_u_core<0>(fc3_w, fc3_b, fca_w, fca_b, u, c0, red);
}

// ---------------- operand loaders ----------------
struct AldF32 {
    const float* p; int ld;
    DI float ld_(int m, int k, bool ok) const { return ok ? p[m * ld + k] : 0.f; }
};
template <int F> struct AldRaw {
    const void* p; int ld;
    DI float ld_(int m, int k, bool ok) const { return ok ? LD<F>(p, m * ld + k) : 0.f; }
};
struct AldCat {   // row m = [nodes[m,:1024] | g[m,:1024]]
    const float* nd; const float* gg;
    DI float ld_(int m, int k, bool ok) const {
        if (!ok) return 0.f;
        const float* s = (k < 1024) ? nd : gg;
        return s[m * 1024 + (k & 1023)];
    }
};
template <int F> struct AldU5 {  // rn = sigmoid(ar + u3x + b4 + u3b) * nodes (fused ew_r)
    const float* ar; const float* u3x; const float* nodes;
    const void* b4; const void* u3b;
    DI float ld_(int m, int k, bool ok) const {
        if (!ok) return 0.f;
        int i = m * 1024 + k;
        float r = fast_sigmoid(ar[i] + u3x[i] + LD<F>(b4, k) + LD<F>(u3b, k));
        return r * nodes[i];
    }
};
template <int F> struct Wld {    // W[n,k] (+ W[n,k+dual] for the [a,a] concat fold)
    const void* p; int ld; int dual;
    DI float ld_(int n, int k, bool ok) const {
        if (!ok) return 0.f;
        float w = LD<F>(p, n * ld + k);
        if (dual) w += LD<F>(p, n * ld + k + dual);
        return w;
    }
};

// ================= MFMA GEMM core =================
// Block 256 thr = 4 waves; tile 64x64; K-chunks of 32 via 16x16x32 bf16 MFMA.
// LDS in fragment order: [g16][lane][8] shorts -> conflict-free ds_read_b128.
// wave w: rows m0+16w..+15 (A frag group w), all 64 cols (4 B frags).
// A-frag: lane -> A[m=lane&15][k=quad*8+j]; C/D: row=(lane>>4)*4+reg, col=lane&15.
template <class AL, class WL>
DI void mcore(const AL& A, const WL& W, float* C, int ldc,
              int M, int N, int kb, int ke, int bx, int by) {
    __shared__ short As[4][64][8];
    __shared__ short Ws[4][64][8];
    const int tid = threadIdx.x;
    const int wv = tid >> 6, lane = tid & 63;
    const int m0 = by * BM, n0 = bx * BN;
    f32x4 acc[4] = {};

    for (int k0 = kb; k0 < ke; k0 += 32) {
#pragma unroll
        for (int h = 0; h < 2; h++) {
            int idx = tid + h * 256;          // one float4-group of A: 64m x 32k
            int m = idx >> 3, q = idx & 7;
            int k = 4 * q;                    // local k, groups of 4 stay in one j-octet
            int gm = m0 + m;
            bool ok = gm < M;
            short4v v;
            v.x = f2b(A.ld_(gm, k0 + k,     ok));
            v.y = f2b(A.ld_(gm, k0 + k + 1, ok));
            v.z = f2b(A.ld_(gm, k0 + k + 2, ok));
            v.w = f2b(A.ld_(gm, k0 + k + 3, ok));
            int lp = (m & 15) | ((k >> 3) << 4);
            *(short4v*)&As[m >> 4][lp][k & 7] = v;
        }
#pragma unroll
        for (int h = 0; h < 2; h++) {
            int idx = tid + h * 256;          // W: 64n x 32k
            int n = idx >> 3, q = idx & 7;
            int k = 4 * q;
            int gn = n0 + n;
            bool ok = gn < N;
            short4v v;
            v.x = f2b(W.ld_(gn, k0 + k,     ok));
            v.y = f2b(W.ld_(gn, k0 + k + 1, ok));
            v.z = f2b(W.ld_(gn, k0 + k + 2, ok));
            v.w = f2b(W.ld_(gn, k0 + k + 3, ok));
            int lp = (n & 15) | ((k >> 3) << 4);
            *(short4v*)&Ws[n >> 4][lp][k & 7] = v;
        }
        __syncthreads();
        bf8v af = *(const bf8v*)As[wv][lane];
#pragma unroll
        for (int nf = 0; nf < 4; nf++) {
            bf8v bfr = *(const bf8v*)Ws[nf][lane];
            acc[nf] = __builtin_amdgcn_mfma_f32_16x16x32_bf16(af, bfr, acc[nf], 0, 0, 0);
        }
        __syncthreads();
    }

    const int q = lane >> 4, cc = lane & 15;
#pragma unroll
    for (int nf = 0; nf < 4; nf++) {
        int n = n0 + 16 * nf + cc;
        if (n >= N) continue;
#pragma unroll
        for (int r = 0; r < 4; r++) {
            int m = m0 + 16 * wv + q * 4 + r;
            if (m < M) atomicAdd(&C[m * ldc + n], acc[nf][r]);
        }
    }
}

// fc1: A = raw fmap (dtype per flag), grid (16,13,4), ksl=256
__global__ __launch_bounds__(256) void mfma_in(
    const int* flag, const void* Ap, int lda,
    const void* Wp, int ldw, float* C, int ldc, int M, int N, int K, int ksl) {
    int kb = blockIdx.z * ksl;
    int ke = kb + ksl; if (ke > K) ke = K;
    if (*flag) { AldRaw<1> A{Ap, lda}; Wld<1> W{Wp, ldw, 0};
        mcore(A, W, C, ldc, M, N, kb, ke, blockIdx.x, blockIdx.y); }
    else       { AldRaw<0> A{Ap, lda}; Wld<0> W{Wp, ldw, 0};
        mcore(A, W, C, ldc, M, N, kb, ke, blockIdx.x, blockIdx.y); }
}

// gate: grid.z = job*4 + split (16 slices), each K=256. M=320,N=1024,K=1024.
__global__ __launch_bounds__(256) void mfma_gate(
    const int* flag, const float* a, const float* nodes,
    const void* w3, const void* w4p, const void* w5p, const void* u3,
    float* az, float* ar_, float* ah, float* u3x) {
    int job = blockIdx.z >> 2, s = blockIdx.z & 3;
    const float* Ap; const void* Wp; float* C; int ldw, dual;
    switch (job) {
        case 0:  Ap = a;     Wp = w3;  C = az;  ldw = 2048; dual = 1024; break;
        case 1:  Ap = a;     Wp = w4p; C = ar_; ldw = 2048; dual = 1024; break;
        case 2:  Ap = a;     Wp = w5p; C = ah;  ldw = 2048; dual = 1024; break;
        default: Ap = nodes; Wp = u3;  C = u3x; ldw = 1024; dual = 0;    break;
    }
    int kb = s * 256, ke = kb + 256;
    AldF32 A{Ap, 1024};
    if (*flag) { Wld<1> W{Wp, ldw, dual};
        mcore(A, W, C, 1024, 320, 1024, kb, ke, blockIdx.x, blockIdx.y); }
    else       { Wld<0> W{Wp, ldw, dual};
        mcore(A, W, C, 1024, 320, 1024, kb, ke, blockIdx.x, blockIdx.y); }
}

// u5: fused r-gate A-operand; 4 k-splits of 256.
__global__ __launch_bounds__(256) void mfma_u5(
    const int* flag, const float* ar_, const float* u3x, const float* nodes,
    const void* b4, const void* u3b, const void* u5w, float* u5x) {
    int kb = blockIdx.z * 256, ke = kb + 256;
    if (*flag) { AldU5<1> A{ar_, u3x, nodes, b4, u3b}; Wld<1> W{u5w, 1024, 0};
        mcore(A, W, u5x, 1024, 320, 1024, kb, ke, blockIdx.x, blockIdx.y); }
    else       { AldU5<0> A{ar_, u3x, nodes, b4, u3b}; Wld<0> W{u5w, 1024, 0};
        mcore(A, W, u5x, 1024, 320, 1024, kb, ke, blockIdx.x, blockIdx.y); }
}

// final: fC = [nodes|g] @ fco_w.T ; grid (32,5,4), 4 k-splits of 512.
__global__ __launch_bounds__(256) void mfma_fin(
    const int* flag, const float* nodes, const float* g,
    const void* fco_w, float* fC) {
    int kb = blockIdx.z * 512, ke = kb + 512;
    AldCat A{nodes, g};
    if (*flag) { Wld<1> W{fco_w, 2048, 0};
        mcore(A, W, fC, 2048, 320, 2048, kb, ke, blockIdx.x, blockIdx.y); }
    else       { Wld<0> W{fco_w, 2048, 0};
        mcore(A, W, fC, 2048, 320, 2048, kb, ke, blockIdx.x, blockIdx.y); }
}

__global__ void fin_combine(const int* flag, const float* fC, const void* fco_b,
                            void* out, int n) {
    int i = blockIdx.x * 256 + threadIdx.x;
    if (i >= n) return;
    int c = i & 2047;
    if (*flag) {
        ((float*)out)[i] = fast_tanh(fC[i] + LD<1>(fco_b, c));
    } else {
        ((__hip_bfloat16*)out)[i] = __float2bfloat16(fast_tanh(fC[i] + LD<0>(fco_b, c)));
    }
}

// ---------------- SIMT GEMM (kept only for tiny fc2: M=80,K=300) ----------------
template <class AL, class WL>
DI void gcore(const AL& A, const WL& W, float* C, int ldc,
              int M, int N, int kb, int ke, int bx, int by, int atom) {
    __shared__ float As[BK][BM + 4];
    __shared__ float Ws2[BK][BN + 4];
    const int tid = threadIdx.x;
    const int tx = tid & 15, ty = tid >> 4;
    const int m0 = by * BM, n0 = bx * BN;
    float acc[4][4] = {};

    for (int k0 = kb; k0 < ke; k0 += BK) {
#pragma unroll
        for (int i = 0; i < 4; i++) {
            int idx = tid + i * 256;
            int kk = idx & 15, mm = idx >> 4;
            int m = m0 + mm, k = k0 + kk;
            As[kk][mm] = A.ld_(m, k, m < M && k < ke);
        }
#pragma unroll
        for (int i = 0; i < 4; i++) {
            int idx = tid + i * 256;
            int kk = idx & 15, nn = idx >> 4;
            int n = n0 + nn, k = k0 + kk;
            Ws2[kk][nn] = W.ld_(n, k, n < N && k < ke);
        }
        __syncthreads();
#pragma unroll
        for (int kk = 0; kk < BK; kk++) {
            float4 av = *(const float4*)(&As[kk][ty * 4]);
            float4 wv = *(const float4*)(&Ws2[kk][tx * 4]);
            float a4[4] = {av.x, av.y, av.z, av.w};
            float w4[4] = {wv.x, wv.y, wv.z, wv.w};
#pragma unroll
            for (int i = 0; i < 4; i++)
#pragma unroll
                for (int j = 0; j < 4; j++)
                    acc[i][j] += a4[i] * w4[j];
        }
        __syncthreads();
    }

    for (int i = 0; i < 4; i++) {
        int m = m0 + ty * 4 + i;
        if (m >= M) continue;
        for (int j = 0; j < 4; j++) {
            int n = n0 + tx * 4 + j;
            if (n >= N) continue;
            if (atom) atomicAdd(&C[m * ldc + n], acc[i][j]);
            else      C[m * ldc + n] = acc[i][j];
        }
    }
}

__global__ __launch_bounds__(256) void gemm_in(
    const int* flag, const void* Ap, int lda,
    const void* Wp, int ldw, int wdual,
    float* C, int ldc, int M, int N, int K, int ksl, int atom) {
    int kb = blockIdx.z * ksl;
    int ke = kb + ksl; if (ke > K) ke = K;
    if (*flag) { AldRaw<1> A{Ap, lda}; Wld<1> W{Wp, ldw, wdual};
        gcore(A, W, C, ldc, M, N, kb, ke, blockIdx.x, blockIdx.y, atom); }
    else       { AldRaw<0> A{Ap, lda}; Wld<0> W{Wp, ldw, wdual};
        gcore(A, W, C, ldc, M, N, kb, ke, blockIdx.x, blockIdx.y, atom); }
}

// ---------------- coeff[n,l] = sum_k tanh(f_wh[n,k]*f_wd[l,k])*u[k] + c0 ----------------
__global__ __launch_bounds__(256) void coeff_kernel(
    const float* __restrict__ f_wh, const float* __restrict__ f_wd,
    const float* __restrict__ u, const float* __restrict__ c0p,
    float* __restrict__ s) {
    int n = blockIdx.x;  // 0..783
    __shared__ float fh[1024];
    __shared__ float uu[1024];
    for (int i = threadIdx.x; i < 1024; i += 256) {
        fh[i] = f_wh[n * 1024 + i];
        uu[i] = u[i];
    }
    __syncthreads();
    float c0 = *c0p;
    int wave = threadIdx.x >> 6, lane = threadIdx.x & 63;
    int b = n / 196, hw = n % 196;
    int l0 = blockIdx.y * 40;
    for (int l = l0 + wave; l < l0 + 40; l += 4) {
        const float* fd = f_wd + l * 1024;
        float p = 0.f;
        for (int k = lane; k < 1024; k += 64)
            p += fast_tanh(fh[k] * fd[k]) * uu[k];
        for (int off = 32; off > 0; off >>= 1) p += __shfl_down(p, off);
        if (lane == 0) s[b * PBATCH + hw * LL + l] = p + c0;
    }
}

// ---------------- softmax over contiguous 196-chunks ----------------
__global__ __launch_bounds__(64) void softmax196(float* __restrict__ s) {
    float* p = s + blockIdx.x * 196;
    int lane = threadIdx.x;
    float v[4];
    float mx = -1e30f;
#pragma unroll
    for (int i = 0; i < 4; i++) {
        int idx = lane + i * 64;
        v[i] = (idx < 196) ? p[idx] : -1e30f;
        mx = fmaxf(mx, v[i]);
    }
    for (int off = 32; off > 0; off >>= 1) mx = fmaxf(mx, __shfl_down(mx, off));
    mx = __shfl(mx, 0);
    float sum = 0.f;
#pragma unroll
    for (int i = 0; i < 4; i++) {
        int idx = lane + i * 64;
        if (idx < 196) { v[i] = __expf(v[i] - mx); sum += v[i]; }
    }
    for (int off = 32; off > 0; off >>= 1) sum += __shfl_down(sum, off);
    sum = __shfl(sum, 0);
    float inv = 1.f / sum;
#pragma unroll
    for (int i = 0; i < 4; i++) {
        int idx = lane + i * 64;
        if (idx < 196) p[idx] = v[i] * inv;
    }
}

// ---------------- g[b,l,c] = sum_hw s[..] * fmap ; grid (320, 4) ----------------
template <int F>
DI void g_core(float* co, const float* s, const void* fmap, float* g, float* nodes) {
    int bl = blockIdx.x;
    int b = bl / LL, l = bl % LL;
    for (int i = threadIdx.x; i < 196; i += 256)
        co[i] = s[b * PBATCH + i * LL + l];
    __syncthreads();
    int c = blockIdx.y * 256 + threadIdx.x;
    int base = b * 196 * 1024 + c;
    float acc = 0.f;
    for (int hw = 0; hw < 196; hw++)
        acc += co[hw] * LD<F>(fmap, base + hw * 1024);
    g[bl * 1024 + c] = acc;
    nodes[bl * 1024 + c] = acc;
}

__global__ __launch_bounds__(256) void g_kernel(
    const int* flag, const float* s, const void* fmap, float* g, float* nodes) {
    __shared__ float co[196];
    if (*flag) g_core<1>(co, s, fmap, g, nodes);
    else       g_core<0>(co, s, fmap, g, nodes);
}

// ---------------- a[b,l,c] = sum_m adj[l,m]*nodes[b,m,c] ; grid (320, 4) ----------------
template <int F>
DI void adj_core(float* arw, const void* adj, const float* nodes, float* a) {
    int bl = blockIdx.x;
    int b = bl / LL, l = bl % LL;
    if (threadIdx.x < LL) arw[threadIdx.x] = LD<F>(adj, l * LL + threadIdx.x);
    __syncthreads();
    int c = blockIdx.y * 256 + threadIdx.x;
    float acc = 0.f;
    for (int m = 0; m < LL; m++)
        acc += arw[m] * nodes[(b * LL + m) * 1024 + c];
    a[bl * 1024 + c] = acc;
}

__global__ __launch_bounds__(256) void adj_kernel(
    const int* flag, const void* adj, const float* nodes, float* a) {
    __shared__ float arw[LL];
    if (*flag) adj_core<1>(arw, adj, nodes, a);
    else       adj_core<0>(arw, adj, nodes, a);
}

// ---------------- nodes = (1-z)*nodes + z*tanh(ah+b5+u5x+u5b), z=sigmoid(az+b3+u3x+u3b) ----------------
template <int F>
DI void ewu(const float* az, const float* u3x, const float* ah, const float* u5x,
            const void* b3, const void* u3b, const void* b5, const void* u5b,
            float* nodes, int i) {
    int c = i & 1023;
    float z = fast_sigmoid(az[i] + u3x[i] + LD<F>(b3, c) + LD<F>(u3b, c));
    float h = fast_tanh(ah[i] + u5x[i] + LD<F>(b5, c) + LD<F>(u5b, c));
    nodes[i] = (1.f - z) * nodes[i] + z * h;
}

__global__ void ew_upd(const int* flag,
                       const float* az, const float* u3x, const float* ah, const float* u5x,
                       const void* b3, const void* u3b, const void* b5, const void* u5b,
                       float* nodes, int n) {
    int i = blockIdx.x * 256 + threadIdx.x;
    if (i >= n) return;
    if (*flag) ewu<1>(az, u3x, ah, u5x, b3, u3b, b5, u5b, nodes, i);
    else       ewu<0>(az, u3x, ah, u5x, b3, u3b, b5, u5b, nodes, i);
}

extern "C" void kernel_launch(void* const* d_in, const int* in_sizes, int n_in,
                              void* d_out, int out_size, void* d_ws, size_t ws_size,
                              hipStream_t stream) {
    const void* fmap  = d_in[0];
    const void* word  = d_in[1];
    const void* adjm  = d_in[2];
    const void* fc1_w = d_in[3];
    const void* fc2_w = d_in[4];
    const void* fc3_w = d_in[5];
    const void* fc3_b = d_in[6];
    const void* fca_w = d_in[7];
    const void* fca_b = d_in[8];
    const void* w3    = d_in[9];
    const void* b3    = d_in[10];
    const void* u3    = d_in[11];
    const void* u3b   = d_in[12];
    const void* w4    = d_in[13];
    const void* b4    = d_in[14];
    const void* w5    = d_in[15];
    const void* b5    = d_in[16];
    const void* u5    = d_in[17];
    const void* u5b   = d_in[18];
    const void* fco_w = d_in[19];
    const void* fco_b = d_in[20];

    // ---- workspace: same 9.18 MB footprint proven in R3/R4 ----
    int*   flag  = (int*)d_ws;
    float* ws    = (float*)d_ws + 16;
    float* g     = ws;                  // 327680 (persistent)
    float* nodes = g + 327680;          // 327680 (persistent)
    float* R     = nodes + 327680;      // overlay region (1,638,400 floats)
    // semantic overlay
    float* f_wh = R;                    // 802816
    float* f_wd = f_wh + 802816;        // 81920
    float* u    = f_wd + 81920;         // 1024
    float* c0   = u + 1024;             // 16
    float* s    = c0 + 16;              // 62720
    // GGNN overlay (reuses R)
    float* a    = R;
    float* az   = a + 327680;
    float* ar_  = az + 327680;
    float* ah   = ar_ + 327680;
    float* u3x  = ah + 327680;
    float* u5x  = a;                    // a dead after mfma_gate
    // final overlay (reuses R): fC 655360
    float* fC   = R;

    // ---- dtype detection ----
    detect_dtype<<<1, 256, 0, stream>>>(fc1_w, 4096, flag);

    // ---- semantic stage ----
    prep_u<<<5, 256, 0, stream>>>(flag, fc3_w, fc3_b, fca_w, fca_b, u, c0);
    hipMemsetAsync(f_wh, 0, 802816 * sizeof(float), stream);
    // f_wh = fmap_view(784,1024) @ fc1_w.T — MFMA, split-K 4
    mfma_in<<<dim3(16, 13, 4), 256, 0, stream>>>(flag, fmap, 1024, fc1_w, 1024,
                                                 f_wh, 1024, NPIX, 1024, 1024, 256);
    // f_wd = word(80,300) @ fc2_w.T — tiny, SIMT
    gemm_in<<<dim3(16, 2, 1), 256, 0, stream>>>(flag, word, 300, fc2_w, 300, 0,
                                                f_wd, 1024, LL, 1024, 300, 304, 0);
    coeff_kernel<<<dim3(NPIX, 2), 256, 0, stream>>>(f_wh, f_wd, u, c0, s);
    softmax196<<<320, 64, 0, stream>>>(s);
    g_kernel<<<dim3(320, 4), 256, 0, stream>>>(flag, s, fmap, g, nodes);

    // ---- GGNN: 3 time steps ----
    for (int t = 0; t < 3; t++) {
        adj_kernel<<<dim3(320, 4), 256, 0, stream>>>(flag, adjm, nodes, a);
        hipMemsetAsync(az, 0, 4u * 327680 * sizeof(float), stream);  // az,ar,ah,u3x
        mfma_gate<<<dim3(16, 5, 16), 256, 0, stream>>>(flag, a, nodes, w3, w4, w5, u3,
                                                       az, ar_, ah, u3x);
        hipMemsetAsync(u5x, 0, 327680 * sizeof(float), stream);      // u5x aliases a
        mfma_u5<<<dim3(16, 5, 4), 256, 0, stream>>>(flag, ar_, u3x, nodes, b4, u3b,
                                                    u5, u5x);
        ew_upd<<<1280, 256, 0, stream>>>(flag, az, u3x, ah, u5x,
                                         b3, u3b, b5, u5b, nodes, 327680);
    }

    // ---- output: tanh([nodes|g] @ fco_w.T + fco_b) ----
    hipMemsetAsync(fC, 0, 655360 * sizeof(float), stream);
    mfma_fin<<<dim3(32, 5, 4), 256, 0, stream>>>(flag, nodes, g, fco_w, fC);
    fin_combine<<<2560, 256, 0, stream>>>(flag, fC, fco_b, d_out, 655360);
}

// Round 6
// 470.974 us; speedup vs baseline: 3.7016x; 1.5446x over previous
//
#include <hip/hip_runtime.h>
#include <hip/hip_bf16.h>

#define LL 80
#define NPIX 784
#define PBATCH 15680

#define BM 64
#define BN 64
#define BK 16

#define DI __device__ __forceinline__

typedef short s8v __attribute__((ext_vector_type(8)));     // 8 bf16 = 16B
typedef float f32x4 __attribute__((ext_vector_type(4)));   // MFMA acc

DI float b2f(__hip_bfloat16 x) { return __bfloat162float(x); }

// f32 -> bf16 bits, round-nearest-even
DI short f2b(float x) {
    unsigned int b = __float_as_uint(x);
    b += 0x7fffu + ((b >> 16) & 1u);
    return (short)(b >> 16);
}

// F=1: buffer holds f32; F=0: buffer holds bf16
template <int F> DI float LD(const void* p, int i) {
    if (F) return ((const float*)p)[i];
    return b2f(((const __hip_bfloat16*)p)[i]);
}

DI float fast_tanh(float x) {
    float e = __expf(2.0f * x);
    return 1.0f - 2.0f / (e + 1.0f);
}
DI float fast_sigmoid(float x) { return 1.0f / (1.0f + __expf(-x)); }

// ---------------- dtype probe (proven R3-R5) ----------------
__global__ __launch_bounds__(256) void detect_dtype(const void* probe, int n, int* flag) {
    __shared__ int bad;
    if (threadIdx.x == 0) bad = 0;
    __syncthreads();
    int c = 0;
    for (int i = threadIdx.x; i < n; i += 256) {
        float v = b2f(((const __hip_bfloat16*)probe)[i]);
        if (!(fabsf(v) < 1000.0f)) c++;
    }
    if (c) atomicAdd(&bad, c);
    __syncthreads();
    if (threadIdx.x == 0) *flag = (bad > 8) ? 1 : 0;   // 1 => inputs are f32
}

// ---------------- one-time converts: raw weights -> bf16 ws copies ----------------
__global__ __launch_bounds__(256) void cvt_k(const int* flag, const void* src,
                                             short* __restrict__ dst, int n) {
    int i0 = (blockIdx.x * 256 + threadIdx.x) * 4;
    if (i0 >= n) return;
    if (*flag) {
        const float* s = (const float*)src;
        dst[i0]   = f2b(s[i0]);
        dst[i0+1] = f2b(s[i0+1]);
        dst[i0+2] = f2b(s[i0+2]);
        dst[i0+3] = f2b(s[i0+3]);
    } else {
        const short* s = (const short*)src;
        dst[i0] = s[i0]; dst[i0+1] = s[i0+1]; dst[i0+2] = s[i0+2]; dst[i0+3] = s[i0+3];
    }
}

// wcat[4096][1024]: rows 0-1023 w3 folded, 1024-2047 w4 folded, 2048-3071 w5 folded, 3072-4095 u3
__global__ __launch_bounds__(256) void build_wcat(const int* flag,
    const void* w3, const void* w4, const void* w5, const void* u3,
    short* __restrict__ wcat) {
    int i0 = (blockIdx.x * 256 + threadIdx.x) * 4;   // 4 consecutive k's, same n
    int n = i0 >> 10, k = i0 & 1023;
    int j = n >> 10, r = n & 1023;
    const void* W = (j == 0) ? w3 : (j == 1) ? w4 : (j == 2) ? w5 : u3;
    int f = *flag;
#pragma unroll
    for (int t = 0; t < 4; t++) {
        float v;
        if (j < 3) v = (f ? ((const float*)W)[r*2048 + k+t] + ((const float*)W)[r*2048 + 1024 + k+t]
                          : b2f(((const __hip_bfloat16*)W)[r*2048 + k+t]) +
                            b2f(((const __hip_bfloat16*)W)[r*2048 + 1024 + k+t]));
        else       v = (f ? ((const float*)W)[r*1024 + k+t]
                          : b2f(((const __hip_bfloat16*)W)[r*1024 + k+t]));
        wcat[i0 + t] = f2b(v);
    }
}

// ---------------- u = fca_w @ fc3_w ; c0 = fc3_b . fca_w + fca_b ----------------
template <int F>
DI void prep_u_core(const void* fc3_w, const void* fc3_b,
                    const void* fca_w, const void* fca_b,
                    float* u, float* c0, float* red) {
    if (blockIdx.x < 4) {
        int k = blockIdx.x * 256 + threadIdx.x;
        float acc = 0.f;
        for (int j = 0; j < 1024; j++)
            acc += LD<F>(fca_w, j) * LD<F>(fc3_w, j * 1024 + k);
        u[k] = acc;
    } else {
        float acc = 0.f;
        for (int j = threadIdx.x; j < 1024; j += 256)
            acc += LD<F>(fc3_b, j) * LD<F>(fca_w, j);
        red[threadIdx.x] = acc;
        __syncthreads();
        for (int s = 128; s > 0; s >>= 1) {
            if (threadIdx.x < s) red[threadIdx.x] += red[threadIdx.x + s];
            __syncthreads();
        }
        if (threadIdx.x == 0) *c0 = red[0] + LD<F>(fca_b, 0);
    }
}

__global__ __launch_bounds__(256) void prep_u(
    const int* flag, const void* fc3_w, const void* fc3_b,
    const void* fca_w, const void* fca_b, float* u, float* c0) {
    __shared__ float red[256];
    if (*flag) prep_u_core<1>(fc3_w, fc3_b, fca_w, fca_b, u, c0, red);
    else       prep_u_core<0>(fc3_w, fc3_b, fca_w, fca_b, u, c0, red);
}

// ================= bf16 MFMA GEMM core =================
// 256 thr = 4 waves; 64x64 tile; K-chunks of 32 via 16x16x32 bf16 MFMA.
// Both operands pre-converted bf16, row-major [row][K]. Plain store to f32 C.
// Staging: thread (m = tid&63, q = tid>>6) loads 16B row-chunk, LDS m-fastest
// -> each 16-lane quarter writes 256B contiguous: conflict-free.
DI void mcore_b(const short* __restrict__ A, int lda,
                const short* __restrict__ B, int ldb,
                float* __restrict__ C, int ldc,
                int M, int kb, int ke, int m0, int n0) {
    __shared__ short As[4][64][8];
    __shared__ short Ws[4][64][8];
    const int tid = threadIdx.x;
    const int wv = tid >> 6, lane = tid & 63;
    const int mA = tid & 63, qA = tid >> 6;
    f32x4 acc[4] = {};

    for (int k0 = kb; k0 < ke; k0 += 32) {
        s8v va = {0,0,0,0,0,0,0,0};
        int gm = m0 + mA;
        if (gm < M) va = *(const s8v*)(A + gm * lda + k0 + 8 * qA);
        *(s8v*)&As[mA >> 4][(mA & 15) | (qA << 4)][0] = va;
        s8v vb = *(const s8v*)(B + (n0 + mA) * ldb + k0 + 8 * qA);
        *(s8v*)&Ws[mA >> 4][(mA & 15) | (qA << 4)][0] = vb;
        __syncthreads();
        s8v af = *(const s8v*)&As[wv][lane][0];
#pragma unroll
        for (int nf = 0; nf < 4; nf++) {
            s8v bf = *(const s8v*)&Ws[nf][lane][0];
            acc[nf] = __builtin_amdgcn_mfma_f32_16x16x32_bf16(af, bf, acc[nf], 0, 0, 0);
        }
        __syncthreads();
    }

    const int q = lane >> 4, cc = lane & 15;
#pragma unroll
    for (int nf = 0; nf < 4; nf++) {
        int n = n0 + 16 * nf + cc;
#pragma unroll
        for (int r = 0; r < 4; r++) {
            int m = m0 + 16 * wv + q * 4 + r;
            if (m < M) C[m * ldc + n] = acc[nf][r];
        }
    }
}

// fc1: f_wh partials; grid (16,13,2)
__global__ __launch_bounds__(256) void mfma_fc1(
    const short* __restrict__ fmap_b, const short* __restrict__ fc1w_b,
    float* __restrict__ fhP) {
    int z = blockIdx.z;
    mcore_b(fmap_b, 1024, fc1w_b, 1024, fhP + z * 802816, 1024,
            NPIX, z * 512, z * 512 + 512, blockIdx.y * 64, blockIdx.x * 64);
}

// fused gate: C[320][4096] partials; grid (64,5,2); A = a_b for n<3072, nodes_b for u3 cols
__global__ __launch_bounds__(256) void mfma_gate(
    const short* __restrict__ a_b, const short* __restrict__ nodes_b,
    const short* __restrict__ wcat_b, float* __restrict__ gP) {
    int z = blockIdx.z;
    const short* A = (blockIdx.x >= 48) ? nodes_b : a_b;
    mcore_b(A, 1024, wcat_b, 1024, gP + z * 1310720, 4096,
            320, z * 512, z * 512 + 512, blockIdx.y * 64, blockIdx.x * 64);
}

// u5: partials x4; grid (16,5,4)
__global__ __launch_bounds__(256) void mfma_u5(
    const short* __restrict__ rn_b, const short* __restrict__ u5w_b,
    float* __restrict__ u5P) {
    int z = blockIdx.z;
    mcore_b(rn_b, 1024, u5w_b, 1024, u5P + z * 327680, 1024,
            320, z * 256, z * 256 + 256, blockIdx.y * 64, blockIdx.x * 64);
}

// final: [nodes|g] @ fco_w.T partials; grid (32,5,2); slice 0 k<1024 uses nodes_b, slice 1 g_b
__global__ __launch_bounds__(256) void mfma_fin(
    const short* __restrict__ nodes_b, const short* __restrict__ g_b,
    const short* __restrict__ fcow_b, float* __restrict__ finP) {
    int z = blockIdx.z;
    const short* A = z ? (g_b - 1024) : nodes_b;   // k in [1024,2048) maps into g_b
    mcore_b(A, 1024, fcow_b, 2048, finP + z * 655360, 2048,
            320, z * 1024, z * 1024 + 1024, blockIdx.y * 64, blockIdx.x * 64);
}

__global__ void fin_combine(const int* flag, const float* __restrict__ finP,
                            const void* fco_b, void* out, int n) {
    int i = blockIdx.x * 256 + threadIdx.x;
    if (i >= n) return;
    int c = i & 2047;
    float acc = finP[i] + finP[655360 + i];
    if (*flag) {
        ((float*)out)[i] = fast_tanh(acc + LD<1>(fco_b, c));
    } else {
        ((__hip_bfloat16*)out)[i] = __float2bfloat16(fast_tanh(acc + LD<0>(fco_b, c)));
    }
}

// ---------------- SIMT GEMM (tiny fc2 only: M=80,K=300) ----------------
template <int F>
struct AldRaw {
    const void* p; int ld;
    DI float ld_(int m, int k, bool ok) const { return ok ? LD<F>(p, m * ld + k) : 0.f; }
};
template <int F> struct Wld {
    const void* p; int ld;
    DI float ld_(int n, int k, bool ok) const { return ok ? LD<F>(p, n * ld + k) : 0.f; }
};

template <class AL, class WL>
DI void gcore(const AL& A, const WL& W, float* C, int ldc,
              int M, int N, int K, int bx, int by) {
    __shared__ float As[BK][BM + 4];
    __shared__ float Ws2[BK][BN + 4];
    const int tid = threadIdx.x;
    const int tx = tid & 15, ty = tid >> 4;
    const int m0 = by * BM, n0 = bx * BN;
    float acc[4][4] = {};

    for (int k0 = 0; k0 < K; k0 += BK) {
#pragma unroll
        for (int i = 0; i < 4; i++) {
            int idx = tid + i * 256;
            int kk = idx & 15, mm = idx >> 4;
            int m = m0 + mm, k = k0 + kk;
            As[kk][mm] = A.ld_(m, k, m < M && k < K);
        }
#pragma unroll
        for (int i = 0; i < 4; i++) {
            int idx = tid + i * 256;
            int kk = idx & 15, nn = idx >> 4;
            int n = n0 + nn, k = k0 + kk;
            Ws2[kk][nn] = W.ld_(n, k, n < N && k < K);
        }
        __syncthreads();
#pragma unroll
        for (int kk = 0; kk < BK; kk++) {
            float4 av = *(const float4*)(&As[kk][ty * 4]);
            float4 wv = *(const float4*)(&Ws2[kk][tx * 4]);
            float a4[4] = {av.x, av.y, av.z, av.w};
            float w4[4] = {wv.x, wv.y, wv.z, wv.w};
#pragma unroll
            for (int i = 0; i < 4; i++)
#pragma unroll
                for (int j = 0; j < 4; j++)
                    acc[i][j] += a4[i] * w4[j];
        }
        __syncthreads();
    }

    for (int i = 0; i < 4; i++) {
        int m = m0 + ty * 4 + i;
        if (m >= M) continue;
        for (int j = 0; j < 4; j++) {
            int n = n0 + tx * 4 + j;
            if (n >= N) continue;
            C[m * ldc + n] = acc[i][j];
        }
    }
}

__global__ __launch_bounds__(256) void gemm_fc2(
    const int* flag, const void* word, const void* fc2_w, float* f_wd) {
    if (*flag) { AldRaw<1> A{word, 300}; Wld<1> W{fc2_w, 300};
        gcore(A, W, f_wd, 1024, LL, 1024, 300, blockIdx.x, blockIdx.y); }
    else       { AldRaw<0> A{word, 300}; Wld<0> W{fc2_w, 300};
        gcore(A, W, f_wd, 1024, LL, 1024, 300, blockIdx.x, blockIdx.y); }
}

// ---------------- coeff[n,l] = sum_k tanh(fh[k]*f_wd[l,k])*u[k] + c0 ----------------
// fh row = sum of fc1 partials. torch-view layout: s[b*15680 + hw*80 + l]
__global__ __launch_bounds__(256) void coeff_kernel(
    const float* __restrict__ fhP, const float* __restrict__ f_wd,
    const float* __restrict__ u, const float* __restrict__ c0p,
    float* __restrict__ s) {
    int n = blockIdx.x;  // 0..783
    __shared__ float fh[1024];
    __shared__ float uu[1024];
    for (int i = threadIdx.x; i < 1024; i += 256) {
        fh[i] = fhP[n * 1024 + i] + fhP[802816 + n * 1024 + i];
        uu[i] = u[i];
    }
    __syncthreads();
    float c0 = *c0p;
    int wave = threadIdx.x >> 6, lane = threadIdx.x & 63;
    int b = n / 196, hw = n % 196;
    int l0 = blockIdx.y * 40;
    for (int l = l0 + wave; l < l0 + 40; l += 4) {
        const float* fd = f_wd + l * 1024;
        float p = 0.f;
        for (int k = lane; k < 1024; k += 64)
            p += fast_tanh(fh[k] * fd[k]) * uu[k];
        for (int off = 32; off > 0; off >>= 1) p += __shfl_down(p, off);
        if (lane == 0) s[b * PBATCH + hw * LL + l] = p + c0;
    }
}

// ---------------- softmax over contiguous 196-chunks ----------------
__global__ __launch_bounds__(64) void softmax196(float* __restrict__ s) {
    float* p = s + blockIdx.x * 196;
    int lane = threadIdx.x;
    float v[4];
    float mx = -1e30f;
#pragma unroll
    for (int i = 0; i < 4; i++) {
        int idx = lane + i * 64;
        v[i] = (idx < 196) ? p[idx] : -1e30f;
        mx = fmaxf(mx, v[i]);
    }
    for (int off = 32; off > 0; off >>= 1) mx = fmaxf(mx, __shfl_down(mx, off));
    mx = __shfl(mx, 0);
    float sum = 0.f;
#pragma unroll
    for (int i = 0; i < 4; i++) {
        int idx = lane + i * 64;
        if (idx < 196) { v[i] = __expf(v[i] - mx); sum += v[i]; }
    }
    for (int off = 32; off > 0; off >>= 1) sum += __shfl_down(sum, off);
    sum = __shfl(sum, 0);
    float inv = 1.f / sum;
#pragma unroll
    for (int i = 0; i < 4; i++) {
        int idx = lane + i * 64;
        if (idx < 196) p[idx] = v[i] * inv;
    }
}

// ---------------- g[b,l,c] = sum_hw s[..]*fmap ; writes nodes f32 + nodes_b + g_b ----------------
template <int F>
DI void g_core(float* co, const float* s, const void* fmap,
               float* nodes, short* nodes_b, short* g_b) {
    int bl = blockIdx.x;
    int b = bl / LL, l = bl % LL;
    for (int i = threadIdx.x; i < 196; i += 256)
        co[i] = s[b * PBATCH + i * LL + l];
    __syncthreads();
    int c = blockIdx.y * 256 + threadIdx.x;
    int base = b * 196 * 1024 + c;
    float acc = 0.f;
    for (int hw = 0; hw < 196; hw++)
        acc += co[hw] * LD<F>(fmap, base + hw * 1024);
    int o = bl * 1024 + c;
    nodes[o] = acc;
    short bb = f2b(acc);
    nodes_b[o] = bb;
    g_b[o] = bb;
}

__global__ __launch_bounds__(256) void g_kernel(
    const int* flag, const float* s, const void* fmap,
    float* nodes, short* nodes_b, short* g_b) {
    __shared__ float co[196];
    if (*flag) g_core<1>(co, s, fmap, nodes, nodes_b, g_b);
    else       g_core<0>(co, s, fmap, nodes, nodes_b, g_b);
}

// ---------------- a_b[b,l,c] = bf16( sum_m adj[l,m]*nodes[b,m,c] ) ; grid (320,4) ----------------
template <int F>
DI void adj_core(float* arw, const void* adj, const float* nodes, short* a_b) {
    int bl = blockIdx.x;
    int b = bl / LL, l = bl % LL;
    if (threadIdx.x < LL) arw[threadIdx.x] = LD<F>(adj, l * LL + threadIdx.x);
    __syncthreads();
    int c = blockIdx.y * 256 + threadIdx.x;
    float acc = 0.f;
    for (int m = 0; m < LL; m++)
        acc += arw[m] * nodes[(b * LL + m) * 1024 + c];
    a_b[bl * 1024 + c] = f2b(acc);
}

__global__ __launch_bounds__(256) void adj_kernel(
    const int* flag, const void* adj, const float* nodes, short* a_b) {
    __shared__ float arw[LL];
    if (*flag) adj_core<1>(arw, adj, nodes, a_b);
    else       adj_core<0>(arw, adj, nodes, a_b);
}

// ---------------- rn_b = bf16( sigmoid(ar + u3x + b4 + u3b) * nodes ) ----------------
template <int F>
DI void ew_r_core(const float* gP, const float* nodes,
                  const void* b4, const void* u3b, short* rn_b, int i) {
    int m = i >> 10, c = i & 1023;
    int base = m * 4096;
    float ar = gP[base + 1024 + c] + gP[1310720 + base + 1024 + c];
    float ux = gP[base + 3072 + c] + gP[1310720 + base + 3072 + c];
    float r = fast_sigmoid(ar + ux + LD<F>(b4, c) + LD<F>(u3b, c));
    rn_b[i] = f2b(r * nodes[i]);
}

__global__ void ew_r(const int* flag, const float* gP, const float* nodes,
                     const void* b4, const void* u3b, short* rn_b, int n) {
    int i = blockIdx.x * 256 + threadIdx.x;
    if (i >= n) return;
    if (*flag) ew_r_core<1>(gP, nodes, b4, u3b, rn_b, i);
    else       ew_r_core<0>(gP, nodes, b4, u3b, rn_b, i);
}

// ---------------- nodes = (1-z)*nodes + z*tanh(ah+u5x+b5+u5b), z=sigmoid(az+u3x+b3+u3b) ----------------
template <int F>
DI void ewu(const float* gP, const float* u5P,
            const void* b3, const void* u3b, const void* b5, const void* u5b,
            float* nodes, short* nodes_b, int i) {
    int m = i >> 10, c = i & 1023;
    int base = m * 4096;
    float az = gP[base + c]        + gP[1310720 + base + c];
    float ah = gP[base + 2048 + c] + gP[1310720 + base + 2048 + c];
    float ux = gP[base + 3072 + c] + gP[1310720 + base + 3072 + c];
    float u5x = u5P[i] + u5P[327680 + i] + u5P[655360 + i] + u5P[983040 + i];
    float z = fast_sigmoid(az + ux + LD<F>(b3, c) + LD<F>(u3b, c));
    float h = fast_tanh(ah + u5x + LD<F>(b5, c) + LD<F>(u5b, c));
    float nd = (1.f - z) * nodes[i] + z * h;
    nodes[i] = nd;
    nodes_b[i] = f2b(nd);
}

__global__ void ew_upd(const int* flag, const float* gP, const float* u5P,
                       const void* b3, const void* u3b, const void* b5, const void* u5b,
                       float* nodes, short* nodes_b, int n) {
    int i = blockIdx.x * 256 + threadIdx.x;
    if (i >= n) return;
    if (*flag) ewu<1>(gP, u5P, b3, u3b, b5, u5b, nodes, nodes_b, i);
    else       ewu<0>(gP, u5P, b3, u3b, b5, u5b, nodes, nodes_b, i);
}

extern "C" void kernel_launch(void* const* d_in, const int* in_sizes, int n_in,
                              void* d_out, int out_size, void* d_ws, size_t ws_size,
                              hipStream_t stream) {
    const void* fmap  = d_in[0];
    const void* word  = d_in[1];
    const void* adjm  = d_in[2];
    const void* fc1_w = d_in[3];
    const void* fc2_w = d_in[4];
    const void* fc3_w = d_in[5];
    const void* fc3_b = d_in[6];
    const void* fca_w = d_in[7];
    const void* fca_b = d_in[8];
    const void* w3    = d_in[9];
    const void* b3    = d_in[10];
    const void* u3    = d_in[11];
    const void* u3b   = d_in[12];
    const void* w4    = d_in[13];
    const void* b4    = d_in[14];
    const void* w5    = d_in[15];
    const void* b5    = d_in[16];
    const void* u5    = d_in[17];
    const void* u5b   = d_in[18];
    const void* fco_w = d_in[19];
    const void* fco_b = d_in[20];

    // ---- workspace layout: ~30.2 MB total, phase-overlaid ----
    int*   flag    = (int*)d_ws;
    float* P       = (float*)d_ws + 16;
    float* nodes   = P;                       P += 327680;   // f32, persistent
    short* nodes_b = (short*)P;               P += 163840;   // bf16 copies
    short* g_b     = (short*)P;               P += 163840;
    short* a_b     = (short*)P;               P += 163840;
    short* rn_b    = (short*)P;               P += 163840;
    short* u5w_b   = (short*)P;               P += 524288;   // 1024x1024 bf16
    short* wcat_b  = (short*)P;               P += 2097152;  // 4096x1024 bf16
    float* R       = P;                                      // overlay, 3,932,160 f
    // semantic phase
    float* fhP    = R;                        // 2 x 802816
    float* f_wd   = R + 1605632;              // 81920
    float* u      = f_wd + 81920;             // 1024
    float* c0     = u + 1024;                 // 16
    float* s      = c0 + 16;                  // 62720
    short* fmap_b = (short*)(s + 62720);      // 802816 shorts
    short* fc1w_b = (short*)(s + 62720 + 401408); // 1048576 shorts
    // GGNN phase (overlays semantic)
    float* gP     = R;                        // 2 x 1310720
    float* u5P    = R + 2621440;              // 4 x 327680
    // final phase (overlays GGNN)
    float* finP   = R;                        // 2 x 655360
    short* fcow_b = (short*)(R + 1310720);    // 4194304 shorts

    // ---- dtype detection ----
    detect_dtype<<<1, 256, 0, stream>>>(fc1_w, 4096, flag);

    // ---- semantic stage ----
    cvt_k<<<784, 256, 0, stream>>>(flag, fmap, fmap_b, 802816);
    cvt_k<<<1024, 256, 0, stream>>>(flag, fc1_w, fc1w_b, 1048576);
    prep_u<<<5, 256, 0, stream>>>(flag, fc3_w, fc3_b, fca_w, fca_b, u, c0);
    mfma_fc1<<<dim3(16, 13, 2), 256, 0, stream>>>(fmap_b, fc1w_b, fhP);
    gemm_fc2<<<dim3(16, 2), 256, 0, stream>>>(flag, word, fc2_w, f_wd);
    coeff_kernel<<<dim3(NPIX, 2), 256, 0, stream>>>(fhP, f_wd, u, c0, s);
    softmax196<<<320, 64, 0, stream>>>(s);
    g_kernel<<<dim3(320, 4), 256, 0, stream>>>(flag, s, fmap, nodes, nodes_b, g_b);

    // ---- GGNN weight prep (once) ----
    cvt_k<<<1024, 256, 0, stream>>>(flag, u5, u5w_b, 1048576);
    build_wcat<<<4096, 256, 0, stream>>>(flag, w3, w4, w5, u3, wcat_b);

    // ---- GGNN: 3 time steps (no atomics, partial-buffer split-K) ----
    for (int t = 0; t < 3; t++) {
        adj_kernel<<<dim3(320, 4), 256, 0, stream>>>(flag, adjm, nodes, a_b);
        mfma_gate<<<dim3(64, 5, 2), 256, 0, stream>>>(a_b, nodes_b, wcat_b, gP);
        ew_r<<<1280, 256, 0, stream>>>(flag, gP, nodes, b4, u3b, rn_b, 327680);
        mfma_u5<<<dim3(16, 5, 4), 256, 0, stream>>>(rn_b, u5w_b, u5P);
        ew_upd<<<1280, 256, 0, stream>>>(flag, gP, u5P, b3, u3b, b5, u5b,
                                         nodes, nodes_b, 327680);
    }

    // ---- output: tanh([nodes|g] @ fco_w.T + fco_b) ----
    cvt_k<<<4096, 256, 0, stream>>>(flag, fco_w, fcow_b, 4194304);
    mfma_fin<<<dim3(32, 5, 2), 256, 0, stream>>>(nodes_b, g_b, fcow_b, finP);
    fin_combine<<<2560, 256, 0, stream>>>(flag, finP, fco_b, d_out, 655360);
}

// Round 8
// 393.169 us; speedup vs baseline: 4.4341x; 1.1979x over previous
//
#include <hip/hip_runtime.h>
#include <hip/hip_bf16.h>

#define LL 80
#define NPIX 784
#define PBATCH 15680

#define DI __device__ __forceinline__

typedef short s8v __attribute__((ext_vector_type(8)));     // 8 bf16 = 16B
typedef short short4v __attribute__((ext_vector_type(4))); // 4 bf16 = 8B
typedef float f32x4 __attribute__((ext_vector_type(4)));   // MFMA acc

DI float b2f(__hip_bfloat16 x) { return __bfloat162float(x); }
DI float s2f(short h) { return __uint_as_float(((unsigned int)(unsigned short)h) << 16); }

// f32 -> bf16 bits, round-nearest-even
DI short f2b(float x) {
    unsigned int b = __float_as_uint(x);
    b += 0x7fffu + ((b >> 16) & 1u);
    return (short)(b >> 16);
}

// F=1: buffer holds f32; F=0: buffer holds bf16
template <int F> DI float LD(const void* p, int i) {
    if (F) return ((const float*)p)[i];
    return b2f(((const __hip_bfloat16*)p)[i]);
}

DI float fast_tanh(float x) {
    float e = __expf(2.0f * x);
    return 1.0f - 2.0f / (e + 1.0f);
}
DI float fast_sigmoid(float x) { return 1.0f / (1.0f + __expf(-x)); }

// ---------------- dtype probe (proven R3-R6) ----------------
__global__ __launch_bounds__(256) void detect_dtype(const void* probe, int n, int* flag) {
    __shared__ int bad;
    if (threadIdx.x == 0) bad = 0;
    __syncthreads();
    int c = 0;
    for (int i = threadIdx.x; i < n; i += 256) {
        float v = b2f(((const __hip_bfloat16*)probe)[i]);
        if (!(fabsf(v) < 1000.0f)) c++;
    }
    if (c) atomicAdd(&bad, c);
    __syncthreads();
    if (threadIdx.x == 0) *flag = (bad > 8) ? 1 : 0;   // 1 => inputs are f32
}

// ---------------- prep sub-parts ----------------
DI void cvt_part(int f, const void* src, short* __restrict__ dst, int blk, int n) {
    int i0 = (blk * 256 + threadIdx.x) * 4;
    if (i0 >= n) return;
    if (f) {
        float4 v = *(const float4*)((const float*)src + i0);
        short4v o = { f2b(v.x), f2b(v.y), f2b(v.z), f2b(v.w) };
        *(short4v*)(dst + i0) = o;
    } else {
        *(short4v*)(dst + i0) = *(const short4v*)((const short*)src + i0);
    }
}

// wcat[4096][1024]: rows 0-1023 w3 folded, 1024-2047 w4 folded, 2048-3071 w5 folded, 3072-4095 u3
DI void wcat_part(int f, const void* w3, const void* w4, const void* w5, const void* u3,
                  short* __restrict__ wcat, int blk) {
    int i0 = (blk * 256 + threadIdx.x) * 4;
    int nr = i0 >> 10, k = i0 & 1023;
    int j = nr >> 10, r = nr & 1023;
    const void* W = (j == 0) ? w3 : (j == 1) ? w4 : (j == 2) ? w5 : u3;
    float4 v;
    if (j < 3) {
        if (f) {
            float4 x = *(const float4*)((const float*)W + r * 2048 + k);
            float4 y = *(const float4*)((const float*)W + r * 2048 + 1024 + k);
            v.x = x.x + y.x; v.y = x.y + y.y; v.z = x.z + y.z; v.w = x.w + y.w;
        } else {
            const short* Ws = (const short*)W;
            short4v x = *(const short4v*)(Ws + r * 2048 + k);
            short4v y = *(const short4v*)(Ws + r * 2048 + 1024 + k);
            v.x = s2f(x.x) + s2f(y.x); v.y = s2f(x.y) + s2f(y.y);
            v.z = s2f(x.z) + s2f(y.z); v.w = s2f(x.w) + s2f(y.w);
        }
    } else {
        if (f) v = *(const float4*)((const float*)W + r * 1024 + k);
        else {
            short4v x = *(const short4v*)((const short*)W + r * 1024 + k);
            v.x = s2f(x.x); v.y = s2f(x.y); v.z = s2f(x.z); v.w = s2f(x.w);
        }
    }
    short4v o = { f2b(v.x), f2b(v.y), f2b(v.z), f2b(v.w) };
    *(short4v*)(wcat + i0) = o;
}

template <int F>
DI void prep_u_part(const void* fc3_w, const void* fc3_b,
                    const void* fca_w, const void* fca_b,
                    float* u, float* c0, float* red, int blk) {
    if (blk < 4) {
        int k = blk * 256 + threadIdx.x;
        float acc = 0.f;
        for (int j = 0; j < 1024; j++)
            acc += LD<F>(fca_w, j) * LD<F>(fc3_w, j * 1024 + k);
        u[k] = acc;
    } else {
        float acc = 0.f;
        for (int j = threadIdx.x; j < 1024; j += 256)
            acc += LD<F>(fc3_b, j) * LD<F>(fca_w, j);
        red[threadIdx.x] = acc;
        __syncthreads();
        for (int s = 128; s > 0; s >>= 1) {
            if (threadIdx.x < s) red[threadIdx.x] += red[threadIdx.x + s];
            __syncthreads();
        }
        if (threadIdx.x == 0) *c0 = red[0] + LD<F>(fca_b, 0);
    }
}

// SIMT GEMM for tiny fc2 (M=80,N=1024,K=300), lds = 2176 floats
template <int F>
DI void fc2_part(float* lds, const void* word, const void* fc2_w, float* C, int bx, int by) {
    float* As = lds;            // [16][68]
    float* Ws2 = lds + 1088;    // [16][68]
    const int tid = threadIdx.x;
    const int tx = tid & 15, ty = tid >> 4;
    const int m0 = by * 64, n0 = bx * 64;
    const int M = 80, K = 300;
    float acc[4][4] = {};

    for (int k0 = 0; k0 < K; k0 += 16) {
#pragma unroll
        for (int i = 0; i < 4; i++) {
            int idx = tid + i * 256;
            int kk = idx & 15, mm = idx >> 4;
            int m = m0 + mm, k = k0 + kk;
            As[kk * 68 + mm] = (m < M && k < K) ? LD<F>(word, m * 300 + k) : 0.f;
        }
#pragma unroll
        for (int i = 0; i < 4; i++) {
            int idx = tid + i * 256;
            int kk = idx & 15, nn = idx >> 4;
            int n = n0 + nn, k = k0 + kk;
            Ws2[kk * 68 + nn] = (k < K) ? LD<F>(fc2_w, n * 300 + k) : 0.f;
        }
        __syncthreads();
#pragma unroll
        for (int kk = 0; kk < 16; kk++) {
            float4 av = *(const float4*)(&As[kk * 68 + ty * 4]);
            float4 wv = *(const float4*)(&Ws2[kk * 68 + tx * 4]);
            float a4[4] = {av.x, av.y, av.z, av.w};
            float w4[4] = {wv.x, wv.y, wv.z, wv.w};
#pragma unroll
            for (int i = 0; i < 4; i++)
#pragma unroll
                for (int j = 0; j < 4; j++)
                    acc[i][j] += a4[i] * w4[j];
        }
        __syncthreads();
    }

    for (int i = 0; i < 4; i++) {
        int m = m0 + ty * 4 + i;
        if (m >= M) continue;
        for (int j = 0; j < 4; j++)
            C[m * 1024 + n0 + tx * 4 + j] = acc[i][j];
    }
}

// ONE dispatch for all independent prep work (branch on block range)
__global__ __launch_bounds__(256) void mega_prep(
    const int* flag,
    const void* fmap, const void* fc1_w, const void* u5w,
    const void* w3, const void* w4, const void* w5, const void* u3,
    const void* fc3_w, const void* fc3_b, const void* fca_w, const void* fca_b,
    const void* word, const void* fc2_w,
    short* fmap_b, short* fc1w_b, short* u5w_b, short* wcat_b,
    float* u, float* c0, float* f_wd) {
    __shared__ float lds[2176];
    int f = *flag;
    int bid = blockIdx.x;
    if      (bid < 784)  cvt_part(f, fmap,  fmap_b, bid,        802816);
    else if (bid < 1808) cvt_part(f, fc1_w, fc1w_b, bid - 784,  1048576);
    else if (bid < 2832) cvt_part(f, u5w,   u5w_b,  bid - 1808, 1048576);
    else if (bid < 6928) wcat_part(f, w3, w4, w5, u3, wcat_b, bid - 2832);
    else if (bid < 6933) {
        if (f) prep_u_part<1>(fc3_w, fc3_b, fca_w, fca_b, u, c0, lds, bid - 6928);
        else   prep_u_part<0>(fc3_w, fc3_b, fca_w, fca_b, u, c0, lds, bid - 6928);
    } else {
        int r = bid - 6933;
        if (f) fc2_part<1>(lds, word, fc2_w, f_wd, r & 15, r >> 4);
        else   fc2_part<0>(lds, word, fc2_w, f_wd, r & 15, r >> 4);
    }
}

// stand-alone cvt (fco only — its ws slot overlays GGNN scratch, so runs late)
__global__ __launch_bounds__(256) void cvt_k(const int* flag, const void* src,
                                             short* __restrict__ dst, int n) {
    cvt_part(*flag, src, dst, blockIdx.x, n);
}

// ================= bf16 MFMA GEMM core (proven R6) =================
DI void mcore_b(const short* __restrict__ A, int lda,
                const short* __restrict__ B, int ldb,
                float* __restrict__ C, int ldc,
                int M, int kb, int ke, int m0, int n0) {
    __shared__ short As[4][64][8];
    __shared__ short Ws[4][64][8];
    const int tid = threadIdx.x;
    const int wv = tid >> 6, lane = tid & 63;
    const int mA = tid & 63, qA = tid >> 6;
    f32x4 acc[4] = {};

    for (int k0 = kb; k0 < ke; k0 += 32) {
        s8v va = {0,0,0,0,0,0,0,0};
        int gm = m0 + mA;
        if (gm < M) va = *(const s8v*)(A + gm * lda + k0 + 8 * qA);
        *(s8v*)&As[mA >> 4][(mA & 15) | (qA << 4)][0] = va;
        s8v vb = *(const s8v*)(B + (n0 + mA) * ldb + k0 + 8 * qA);
        *(s8v*)&Ws[mA >> 4][(mA & 15) | (qA << 4)][0] = vb;
        __syncthreads();
        s8v af = *(const s8v*)&As[wv][lane][0];
#pragma unroll
        for (int nf = 0; nf < 4; nf++) {
            s8v bf = *(const s8v*)&Ws[nf][lane][0];
            acc[nf] = __builtin_amdgcn_mfma_f32_16x16x32_bf16(af, bf, acc[nf], 0, 0, 0);
        }
        __syncthreads();
    }

    const int q = lane >> 4, cc = lane & 15;
#pragma unroll
    for (int nf = 0; nf < 4; nf++) {
        int n = n0 + 16 * nf + cc;
#pragma unroll
        for (int r = 0; r < 4; r++) {
            int m = m0 + 16 * wv + q * 4 + r;
            if (m < M) C[m * ldc + n] = acc[nf][r];
        }
    }
}

__global__ __launch_bounds__(256) void mfma_fc1(
    const short* __restrict__ fmap_b, const short* __restrict__ fc1w_b,
    float* __restrict__ fhP) {
    int z = blockIdx.z;
    mcore_b(fmap_b, 1024, fc1w_b, 1024, fhP + z * 802816, 1024,
            NPIX, z * 512, z * 512 + 512, blockIdx.y * 64, blockIdx.x * 64);
}

__global__ __launch_bounds__(256) void mfma_gate(
    const short* __restrict__ a_b, const short* __restrict__ nodes_b,
    const short* __restrict__ wcat_b, float* __restrict__ gP) {
    int z = blockIdx.z;
    const short* A = (blockIdx.x >= 48) ? nodes_b : a_b;
    mcore_b(A, 1024, wcat_b, 1024, gP + z * 1310720, 4096,
            320, z * 512, z * 512 + 512, blockIdx.y * 64, blockIdx.x * 64);
}

__global__ __launch_bounds__(256) void mfma_u5(
    const short* __restrict__ rn_b, const short* __restrict__ u5w_b,
    float* __restrict__ u5P) {
    int z = blockIdx.z;
    mcore_b(rn_b, 1024, u5w_b, 1024, u5P + z * 327680, 1024,
            320, z * 256, z * 256 + 256, blockIdx.y * 64, blockIdx.x * 64);
}

__global__ __launch_bounds__(256) void mfma_fin(
    const short* __restrict__ nodes_b, const short* __restrict__ g_b,
    const short* __restrict__ fcow_b, float* __restrict__ finP) {
    int z = blockIdx.z;
    const short* A = z ? (g_b - 1024) : nodes_b;   // k in [1024,2048) maps into g_b
    mcore_b(A, 1024, fcow_b, 2048, finP + z * 655360, 2048,
            320, z * 1024, z * 1024 + 1024, blockIdx.y * 64, blockIdx.x * 64);
}

__global__ void fin_combine(const int* flag, const float* __restrict__ finP,
                            const void* fco_b, void* out, int n) {
    int i4 = (blockIdx.x * 256 + threadIdx.x) * 4;
    if (i4 >= n) return;
    int c = i4 & 2047;
    float4 p0 = *(const float4*)(finP + i4);
    float4 p1 = *(const float4*)(finP + 655360 + i4);
    int f = *flag;
    float v0 = fast_tanh(p0.x + p1.x + (f ? LD<1>(fco_b, c)   : LD<0>(fco_b, c)));
    float v1 = fast_tanh(p0.y + p1.y + (f ? LD<1>(fco_b, c+1) : LD<0>(fco_b, c+1)));
    float v2 = fast_tanh(p0.z + p1.z + (f ? LD<1>(fco_b, c+2) : LD<0>(fco_b, c+2)));
    float v3 = fast_tanh(p0.w + p1.w + (f ? LD<1>(fco_b, c+3) : LD<0>(fco_b, c+3)));
    if (f) {
        float4 o = {v0, v1, v2, v3};
        *(float4*)((float*)out + i4) = o;
    } else {
        short4v o = { f2b(v0), f2b(v1), f2b(v2), f2b(v3) };
        *(short4v*)((short*)out + i4) = o;
    }
}

// ---------------- coeff: vectorized float4 ----------------
// coeff[n,l] = sum_k tanh(fh[k]*f_wd[l,k])*u[k] + c0 ; s[b*15680 + hw*80 + l]
__global__ __launch_bounds__(256) void coeff_kernel(
    const float* __restrict__ fhP, const float* __restrict__ f_wd,
    const float* __restrict__ u, const float* __restrict__ c0p,
    float* __restrict__ s) {
    int n = blockIdx.x;  // 0..783
    __shared__ float4 fh4[256];
    __shared__ float4 uu4[256];
    int t = threadIdx.x;
    {
        float4 a0 = *(const float4*)(fhP + n * 1024 + t * 4);
        float4 a1 = *(const float4*)(fhP + 802816 + n * 1024 + t * 4);
        float4 fv = {a0.x + a1.x, a0.y + a1.y, a0.z + a1.z, a0.w + a1.w};
        fh4[t] = fv;
        uu4[t] = *(const float4*)(u + t * 4);
    }
    __syncthreads();
    float c0 = *c0p;
    int wave = t >> 6, lane = t & 63;
    int b = n / 196, hw = n % 196;
    int l0 = blockIdx.y * 40;
    for (int l = l0 + wave; l < l0 + 40; l += 4) {
        const float4* fd4 = (const float4*)(f_wd + l * 1024);
        float p = 0.f;
#pragma unroll
        for (int k = 0; k < 4; k++) {
            int idx = lane + k * 64;
            float4 h = fh4[idx];
            float4 d = fd4[idx];
            float4 uu = uu4[idx];
            p += fast_tanh(h.x * d.x) * uu.x;
            p += fast_tanh(h.y * d.y) * uu.y;
            p += fast_tanh(h.z * d.z) * uu.z;
            p += fast_tanh(h.w * d.w) * uu.w;
        }
        for (int off = 32; off > 0; off >>= 1) p += __shfl_down(p, off);
        if (lane == 0) s[b * PBATCH + hw * LL + l] = p + c0;
    }
}

// ---------------- softmax over contiguous 196-chunks ----------------
__global__ __launch_bounds__(64) void softmax196(float* __restrict__ s) {
    float* p = s + blockIdx.x * 196;
    int lane = threadIdx.x;
    float v[4];
    float mx = -1e30f;
#pragma unroll
    for (int i = 0; i < 4; i++) {
        int idx = lane + i * 64;
        v[i] = (idx < 196) ? p[idx] : -1e30f;
        mx = fmaxf(mx, v[i]);
    }
    for (int off = 32; off > 0; off >>= 1) mx = fmaxf(mx, __shfl_down(mx, off));
    mx = __shfl(mx, 0);
    float sum = 0.f;
#pragma unroll
    for (int i = 0; i < 4; i++) {
        int idx = lane + i * 64;
        if (idx < 196) { v[i] = __expf(v[i] - mx); sum += v[i]; }
    }
    for (int off = 32; off > 0; off >>= 1) sum += __shfl_down(sum, off);
    sum = __shfl(sum, 0);
    float inv = 1.f / sum;
#pragma unroll
    for (int i = 0; i < 4; i++) {
        int idx = lane + i * 64;
        if (idx < 196) p[idx] = v[i] * inv;
    }
}

// ---------------- g: reads bf16 fmap_b, 4 c per thread ----------------
__global__ __launch_bounds__(256) void g_kernel(
    const float* __restrict__ s, const short* __restrict__ fmap_b,
    float* __restrict__ nodes, short* __restrict__ nodes_b, short* __restrict__ g_b) {
    int bl = blockIdx.x;
    int b = bl / LL, l = bl % LL;
    __shared__ float co[196];
    for (int i = threadIdx.x; i < 196; i += 256)
        co[i] = s[b * PBATCH + i * LL + l];
    __syncthreads();
    int c4 = threadIdx.x * 4;
    const short* base = fmap_b + b * 196 * 1024 + c4;
    float a0 = 0.f, a1 = 0.f, a2 = 0.f, a3 = 0.f;
    for (int hw = 0; hw < 196; hw++) {
        short4v v = *(const short4v*)(base + hw * 1024);
        float w = co[hw];
        a0 += w * s2f(v.x); a1 += w * s2f(v.y);
        a2 += w * s2f(v.z); a3 += w * s2f(v.w);
    }
    int o = bl * 1024 + c4;
    float4 fa = {a0, a1, a2, a3};
    *(float4*)(nodes + o) = fa;
    short4v bb = { f2b(a0), f2b(a1), f2b(a2), f2b(a3) };
    *(short4v*)(nodes_b + o) = bb;
    *(short4v*)(g_b + o) = bb;
}

// ---------------- adj: 4 c per thread ----------------
template <int F>
DI void adj_core(float* arw, const void* adj, const float* nodes, short* a_b) {
    int bl = blockIdx.x;
    int b = bl / LL, l = bl % LL;
    if (threadIdx.x < LL) arw[threadIdx.x] = LD<F>(adj, l * LL + threadIdx.x);
    __syncthreads();
    int c4 = threadIdx.x * 4;
    const float* nb = nodes + b * LL * 1024 + c4;
    float a0 = 0.f, a1 = 0.f, a2 = 0.f, a3 = 0.f;
    for (int m = 0; m < LL; m++) {
        float am = arw[m];
        float4 nd = *(const float4*)(nb + m * 1024);
        a0 += am * nd.x; a1 += am * nd.y; a2 += am * nd.z; a3 += am * nd.w;
    }
    short4v bb = { f2b(a0), f2b(a1), f2b(a2), f2b(a3) };
    *(short4v*)(a_b + bl * 1024 + c4) = bb;
}

__global__ __launch_bounds__(256) void adj_kernel(
    const int* flag, const void* adj, const float* nodes, short* a_b) {
    __shared__ float arw[LL];
    if (*flag) adj_core<1>(arw, adj, nodes, a_b);
    else       adj_core<0>(arw, adj, nodes, a_b);
}

// ---------------- rn_b = bf16( sigmoid(ar + u3x + b4 + u3b) * nodes ), x4 ----------------
template <int F>
DI void ew_r_core(const float* gP, const float* nodes,
                  const void* b4, const void* u3b, short* rn_b, int i4) {
    int m = i4 >> 10, c = i4 & 1023;
    int base = m * 4096;
    float4 r0 = *(const float4*)(gP + base + 1024 + c);
    float4 r1 = *(const float4*)(gP + 1310720 + base + 1024 + c);
    float4 x0 = *(const float4*)(gP + base + 3072 + c);
    float4 x1 = *(const float4*)(gP + 1310720 + base + 3072 + c);
    float4 nd = *(const float4*)(nodes + i4);
    short4v o;
    o.x = f2b(fast_sigmoid(r0.x + r1.x + x0.x + x1.x + LD<F>(b4, c)   + LD<F>(u3b, c))   * nd.x);
    o.y = f2b(fast_sigmoid(r0.y + r1.y + x0.y + x1.y + LD<F>(b4, c+1) + LD<F>(u3b, c+1)) * nd.y);
    o.z = f2b(fast_sigmoid(r0.z + r1.z + x0.z + x1.z + LD<F>(b4, c+2) + LD<F>(u3b, c+2)) * nd.z);
    o.w = f2b(fast_sigmoid(r0.w + r1.w + x0.w + x1.w + LD<F>(b4, c+3) + LD<F>(u3b, c+3)) * nd.w);
    *(short4v*)(rn_b + i4) = o;
}

__global__ void ew_r(const int* flag, const float* gP, const float* nodes,
                     const void* b4, const void* u3b, short* rn_b, int n) {
    int i4 = (blockIdx.x * 256 + threadIdx.x) * 4;
    if (i4 >= n) return;
    if (*flag) ew_r_core<1>(gP, nodes, b4, u3b, rn_b, i4);
    else       ew_r_core<0>(gP, nodes, b4, u3b, rn_b, i4);
}

// ---------------- nodes = (1-z)*nodes + z*tanh(ah+u5x+b5+u5b), z=sigmoid(az+u3x+b3+u3b), x4 ----------------
template <int F>
DI void ewu(const float* gP, const float* u5P,
            const void* b3, const void* u3b, const void* b5, const void* u5b,
            float* nodes, short* nodes_b, int i4) {
    int m = i4 >> 10, c = i4 & 1023;
    int base = m * 4096;
    float4 z0 = *(const float4*)(gP + base + c);
    float4 z1 = *(const float4*)(gP + 1310720 + base + c);
    float4 h0 = *(const float4*)(gP + base + 2048 + c);
    float4 h1 = *(const float4*)(gP + 1310720 + base + 2048 + c);
    float4 x0 = *(const float4*)(gP + base + 3072 + c);
    float4 x1 = *(const float4*)(gP + 1310720 + base + 3072 + c);
    float4 u0 = *(const float4*)(u5P + i4);
    float4 u1 = *(const float4*)(u5P + 327680 + i4);
    float4 u2 = *(const float4*)(u5P + 655360 + i4);
    float4 u3v = *(const float4*)(u5P + 983040 + i4);
    float4 nd = *(const float4*)(nodes + i4);
    float4 out;
#define EWU1(CH, CO) { \
    float z = fast_sigmoid(z0.CH + z1.CH + x0.CH + x1.CH + LD<F>(b3, c+CO) + LD<F>(u3b, c+CO)); \
    float h = fast_tanh(h0.CH + h1.CH + u0.CH + u1.CH + u2.CH + u3v.CH + LD<F>(b5, c+CO) + LD<F>(u5b, c+CO)); \
    out.CH = (1.f - z) * nd.CH + z * h; }
    EWU1(x, 0) EWU1(y, 1) EWU1(z, 2) EWU1(w, 3)
#undef EWU1
    *(float4*)(nodes + i4) = out;
    short4v bb = { f2b(out.x), f2b(out.y), f2b(out.z), f2b(out.w) };
    *(short4v*)(nodes_b + i4) = bb;
}

__global__ void ew_upd(const int* flag, const float* gP, const float* u5P,
                       const void* b3, const void* u3b, const void* b5, const void* u5b,
                       float* nodes, short* nodes_b, int n) {
    int i4 = (blockIdx.x * 256 + threadIdx.x) * 4;
    if (i4 >= n) return;
    if (*flag) ewu<1>(gP, u5P, b3, u3b, b5, u5b, nodes, nodes_b, i4);
    else       ewu<0>(gP, u5P, b3, u3b, b5, u5b, nodes, nodes_b, i4);
}

extern "C" void kernel_launch(void* const* d_in, const int* in_sizes, int n_in,
                              void* d_out, int out_size, void* d_ws, size_t ws_size,
                              hipStream_t stream) {
    const void* fmap  = d_in[0];
    const void* word  = d_in[1];
    const void* adjm  = d_in[2];
    const void* fc1_w = d_in[3];
    const void* fc2_w = d_in[4];
    const void* fc3_w = d_in[5];
    const void* fc3_b = d_in[6];
    const void* fca_w = d_in[7];
    const void* fca_b = d_in[8];
    const void* w3    = d_in[9];
    const void* b3    = d_in[10];
    const void* u3    = d_in[11];
    const void* u3b   = d_in[12];
    const void* w4    = d_in[13];
    const void* b4    = d_in[14];
    const void* w5    = d_in[15];
    const void* b5    = d_in[16];
    const void* u5    = d_in[17];
    const void* u5b   = d_in[18];
    const void* fco_w = d_in[19];
    const void* fco_b = d_in[20];

    // ---- workspace — increments are in FLOATS (bf16 buffers need elems/2).
    // R7's NaN was exactly this: halved short-buffer slots overran into the
    // overlay region. Sizes below match the proven R6 footprint (30.1 MB).
    int*   flag    = (int*)d_ws;
    float* P       = (float*)d_ws + 16;
    float* nodes   = P;                       P += 327680;   // f32, persistent
    short* nodes_b = (short*)P;               P += 163840;   // 327680 bf16
    short* g_b     = (short*)P;               P += 163840;   // 327680 bf16
    short* a_b     = (short*)P;               P += 163840;   // 327680 bf16
    short* rn_b    = (short*)P;               P += 163840;   // 327680 bf16
    short* u5w_b   = (short*)P;               P += 524288;   // 1048576 bf16
    short* wcat_b  = (short*)P;               P += 2097152;  // 4194304 bf16
    float* R       = P;                                      // overlay, 3,932,160 f
    // semantic phase
    float* fhP    = R;                        // 2 x 802816
    float* f_wd   = R + 1605632;              // 81920
    float* u      = f_wd + 81920;             // 1024
    float* c0     = u + 1024;                 // 16
    float* s      = c0 + 16;                  // 62720
    short* fmap_b = (short*)(s + 62720);      // 802816 shorts = 401408 f
    short* fc1w_b = (short*)(s + 62720 + 401408); // 1048576 shorts = 524288 f
    // GGNN phase (overlays semantic)
    float* gP     = R;                        // 2 x 1310720
    float* u5P    = R + 2621440;              // 4 x 327680
    // final phase (overlays GGNN)
    float* finP   = R;                        // 2 x 655360
    short* fcow_b = (short*)(R + 1310720);    // 4194304 shorts = 2097152 f

    // ---- dtype detection ----
    detect_dtype<<<1, 256, 0, stream>>>(fc1_w, 4096, flag);

    // ---- all independent prep in ONE dispatch ----
    mega_prep<<<6965, 256, 0, stream>>>(flag, fmap, fc1_w, u5,
                                        w3, w4, w5, u3,
                                        fc3_w, fc3_b, fca_w, fca_b,
                                        word, fc2_w,
                                        fmap_b, fc1w_b, u5w_b, wcat_b,
                                        u, c0, f_wd);

    // ---- semantic stage ----
    mfma_fc1<<<dim3(16, 13, 2), 256, 0, stream>>>(fmap_b, fc1w_b, fhP);
    coeff_kernel<<<dim3(NPIX, 2), 256, 0, stream>>>(fhP, f_wd, u, c0, s);
    softmax196<<<320, 64, 0, stream>>>(s);
    g_kernel<<<320, 256, 0, stream>>>(s, fmap_b, nodes, nodes_b, g_b);

    // ---- GGNN: 3 time steps ----
    for (int t = 0; t < 3; t++) {
        adj_kernel<<<320, 256, 0, stream>>>(flag, adjm, nodes, a_b);
        mfma_gate<<<dim3(64, 5, 2), 256, 0, stream>>>(a_b, nodes_b, wcat_b, gP);
        ew_r<<<320, 256, 0, stream>>>(flag, gP, nodes, b4, u3b, rn_b, 327680);
        mfma_u5<<<dim3(16, 5, 4), 256, 0, stream>>>(rn_b, u5w_b, u5P);
        ew_upd<<<320, 256, 0, stream>>>(flag, gP, u5P, b3, u3b, b5, u5b,
                                        nodes, nodes_b, 327680);
    }

    // ---- output: tanh([nodes|g] @ fco_w.T + fco_b) ----
    cvt_k<<<4096, 256, 0, stream>>>(flag, fco_w, fcow_b, 4194304);
    mfma_fin<<<dim3(32, 5, 2), 256, 0, stream>>>(nodes_b, g_b, fcow_b, finP);
    fin_combine<<<640, 256, 0, stream>>>(flag, finP, fco_b, d_out, 655360);
}